// Round 17
// baseline (585.605 us; speedup 1.0000x reference)
//
#include <hip/hip_runtime.h>
#include <math.h>

#define R_ 512
#define C_ 512
#define E_ 256
#define H_ 8
#define D_ 32
#define RC_ (R_*C_)   // 262144
#define RP 136        // repack pitch (ushorts)

typedef __attribute__((ext_vector_type(8))) short bf16x8;
typedef __attribute__((ext_vector_type(4))) float f32x4;

__device__ __forceinline__ ushort f2bf(float f) {
    union { float f; unsigned u; } v; v.f = f;
    unsigned r = v.u + 0x7FFFu + ((v.u >> 16) & 1u);   // RNE
    return (ushort)(r >> 16);
}
__device__ __forceinline__ float bf2f(ushort u) {
    union { unsigned u; float f; } v; v.u = ((unsigned)u) << 16;
    return v.f;
}
// packed f32x2 -> bf16x2 (RNE on gfx950)
__device__ __forceinline__ unsigned cvtpk(float lo, float hi) {
    unsigned r;
    asm("v_cvt_pk_bf16_f32 %0, %1, %2" : "=v"(r) : "v"(lo), "v"(hi));
    return r;
}

// 16B global->LDS direct copy (lane-linear dest), fallback = reg staging.
__device__ __forceinline__ void gll16(const ushort* g, ushort* l) {
#if __has_builtin(__builtin_amdgcn_global_load_lds)
    __builtin_amdgcn_global_load_lds(
        (const __attribute__((address_space(1))) unsigned*)(unsigned long long)g,
        (__attribute__((address_space(3))) unsigned*)(unsigned)(unsigned long long)l,
        16, 0, 0);
#else
    *(uint4*)l = *(const uint4*)g;
#endif
}

// Stage one 16B chunk f of a [rows][32-ushort] bf16 tile.  Source slot
// XOR-swizzled with (row>>1)&3 (r12-proven key).  LDS dest lane-linear.
#define SCH(gbase, stride, lds, f)                                               \
    gll16((gbase) + (size_t)((f) >> 2) * (stride)                                \
              + (((((f) & 3) ^ ((((f) >> 2) >> 1) & 3))) << 3),                  \
          (lds) + (f) * 8)

// --- Fenced sync primitives (validated r11/r12: rule #18 double-fence).
#define SCHED0   __builtin_amdgcn_sched_barrier(0)
#define ABAR     __builtin_amdgcn_s_barrier()
#define VMCNT(N) asm volatile("s_waitcnt vmcnt(" #N ")" ::: "memory")
#define LGKM0    asm volatile("s_waitcnt lgkmcnt(0)" ::: "memory")

// 512-thread / 8-wave (2x4) preamble: wave = 64m x 32n, acc[4][2].
#define PREAMBLE8                                       \
    const int t = threadIdx.x;                          \
    const int wid = t >> 6, l = t & 63;                 \
    const int wm = wid >> 2, wn = wid & 3;              \
    const int l15 = l & 15, lhi = l >> 4;               \
    const int swz8 = (lhi ^ ((l15 >> 1) & 3)) * 8;      \
    f32x4 acc[4][2];                                    \
    _Pragma("unroll")                                   \
    for (int a_ = 0; a_ < 4; ++a_)                      \
        _Pragma("unroll")                               \
        for (int b_ = 0; b_ < 2; ++b_)                  \
            acc[a_][b_] = (f32x4){0.f, 0.f, 0.f, 0.f};

#define MFMA_STEP8(As, Bs)                                                       \
    {                                                                            \
        bf16x8 af_[4], bf_[2];                                                   \
        _Pragma("unroll")                                                        \
        for (int f_ = 0; f_ < 4; ++f_)                                           \
            af_[f_] = *(const bf16x8*)((As) + (wm*64 + f_*16 + l15)*32 + swz8);  \
        _Pragma("unroll")                                                        \
        for (int g_ = 0; g_ < 2; ++g_)                                           \
            bf_[g_] = *(const bf16x8*)((Bs) + (wn*32 + g_*16 + l15)*32 + swz8);  \
        _Pragma("unroll")                                                        \
        for (int m_ = 0; m_ < 4; ++m_)                                           \
            _Pragma("unroll")                                                    \
            for (int n_ = 0; n_ < 2; ++n_)                                       \
                acc[m_][n_] = __builtin_amdgcn_mfma_f32_16x16x32_bf16(           \
                    af_[m_], bf_[n_], acc[m_][n_], 0, 0, 0);                     \
    }

// Triple-buffered K-loop, ONE fenced barrier per step, prefetch distance 2
// (validated r12), 512-thread variant: each STG = 2 gll16/thread, VMCNT(2).
#define DBUFT8(STG, NIT)                                                         \
    STG(0, A0, B0); STG(1, A1, B1);                                              \
    _Pragma("unroll")                                                            \
    for (int s = 0; s < (NIT); ++s) {                                            \
        if (s < (NIT) - 1) { VMCNT(2); } else { VMCNT(0); }                      \
        SCHED0; ABAR; SCHED0;                                                    \
        if (s + 2 < (NIT)) {                                                     \
            if (((s + 2) % 3) == 0)      { STG(s + 2, A0, B0); }                 \
            else if (((s + 2) % 3) == 1) { STG(s + 2, A1, B1); }                 \
            else                         { STG(s + 2, A2, B2); }                 \
        }                                                                        \
        if ((s % 3) == 0)      { MFMA_STEP8(A0, B0); }                           \
        else if ((s % 3) == 1) { MFMA_STEP8(A1, B1); }                           \
        else                   { MFMA_STEP8(A2, B2); }                           \
    }

#define BUFS3 ushort* A0 = S;          ushort* B0 = S + 4096;                    \
              ushort* A1 = S + 8192;   ushort* B1 = S + 12288;                   \
              ushort* A2 = S + 16384;  ushort* B2 = S + 20480;

// ---------------------------------------------------------------------------
// Weights -> n-major bf16.
// ---------------------------------------------------------------------------
__global__ __launch_bounds__(256) void convert_w(
    const float* __restrict__ Wq, const float* __restrict__ Wk,
    const float* __restrict__ Wv, const float* __restrict__ Wo,
    ushort* __restrict__ WTqkv, ushort* __restrict__ WoT)
{
    const int id = blockIdx.x;      // 0..1023
    const int matn = id >> 8;
    const int n = id & 255;
    const int k = threadIdx.x;
    const float* W = (matn == 0) ? Wq : (matn == 1) ? Wk : (matn == 2) ? Wv : Wo;
    ushort v = f2bf(W[(size_t)k * E_ + n]);
    if (matn < 3) WTqkv[((size_t)matn * E_ + n) * E_ + k] = v;
    else          WoT[(size_t)n * E_ + k] = v;
}

// ---------------------------------------------------------------------------
// Fused QKV projection: 512 threads (8 waves 2x4), 128x128 tile.  Fenced
// reg-staged schedule (r16, passing): 2 A float4 + 1 B gll per thread,
// VMCNT(3); LDS 40KB -> 4 blocks/CU x 8 waves.
// ---------------------------------------------------------------------------
__global__ __launch_bounds__(512) void qkv_mfma(
    const float* __restrict__ x, const ushort* __restrict__ WT,
    const float* __restrict__ bq, const float* __restrict__ bk,
    const float* __restrict__ bv, const float* __restrict__ mask,
    ushort* __restrict__ qb, ushort* __restrict__ kb, ushort* __restrict__ vb)
{
    __shared__ __align__(16) ushort S[20480];   // 40KB; repack aliases front
    ushort* Ab0 = S;            // bf16 [128][32]
    ushort* Ab1 = S + 4096;
    ushort* Bb0 = S + 8192;
    ushort* Bb1 = S + 12288;
    ushort* Bb2 = S + 16384;
    const int id = ((blockIdx.x & 7) * 1536) + (blockIdx.x >> 3);
    const int nt = id % 6;
    const int rc0 = (id / 6) * 128;
    PREAMBLE8;

    const float*  Ag = x + (size_t)rc0 * E_;
    const ushort* Bg = WT + (size_t)nt * 128 * E_;

    // A: thread t owns one bf16 16B chunk: row = t>>2, slot = t&3;
    // source fp32 chunk cc = slot ^ ((row>>1)&3) (r12 key).
    const int rowA = t >> 2;
    const int ccA = (t & 3) ^ ((rowA >> 1) & 3);
    const float* Ap = Ag + (size_t)rowA * E_ + ccA * 8;
    const int wsA = rowA * 32 + (t & 3) * 8;

    float4 rA0a, rA0b;   // reg set 0 (even steps)
    float4 rA1a, rA1b;   // reg set 1 (odd steps)

#define ALOAD0(i) { rA0a = *(const float4*)(Ap + (i)*32);                        \
                    rA0b = *(const float4*)(Ap + (i)*32 + 4); }
#define ALOAD1(i) { rA1a = *(const float4*)(Ap + (i)*32);                        \
                    rA1b = *(const float4*)(Ap + (i)*32 + 4); }
#define AWRITE0(buf) { uint4 w_ = { cvtpk(rA0a.x,rA0a.y), cvtpk(rA0a.z,rA0a.w),  \
                                    cvtpk(rA0b.x,rA0b.y), cvtpk(rA0b.z,rA0b.w)}; \
                       *(uint4*)((buf) + wsA) = w_; }
#define AWRITE1(buf) { uint4 w_ = { cvtpk(rA1a.x,rA1a.y), cvtpk(rA1a.z,rA1a.w),  \
                                    cvtpk(rA1b.x,rA1b.y), cvtpk(rA1b.z,rA1b.w)}; \
                       *(uint4*)((buf) + wsA) = w_; }
#define BGLL(i, buf) { const ushort* Bi_ = Bg + (i) * 32;                        \
                       SCH(Bi_, E_, buf, t); }

    // Prologue: batches 0 and 1 (each = 2 A float4 loads + 1 B gll).
    ALOAD0(0); BGLL(0, Bb0);
    ALOAD1(1); BGLL(1, Bb1);

    #pragma unroll
    for (int s = 0; s < 8; ++s) {
        if (s < 7) { VMCNT(3); } else { VMCNT(0); }   // batch s landed
        SCHED0;
        if ((s & 1) == 0) { AWRITE0((s & 1) ? Ab1 : Ab0); }
        else              { AWRITE1((s & 1) ? Ab1 : Ab0); }
        LGKM0; SCHED0; ABAR; SCHED0;
        if (s + 2 < 8) {
            if ((s & 1) == 0) { ALOAD0(s + 2); }       // reuse set s&1
            else              { ALOAD1(s + 2); }
            if (((s + 2) % 3) == 0)      { BGLL(s + 2, Bb0); }
            else if (((s + 2) % 3) == 1) { BGLL(s + 2, Bb1); }
            else                         { BGLL(s + 2, Bb2); }
        }
        if ((s % 3) == 0)      { MFMA_STEP8(((s & 1) ? Ab1 : Ab0), Bb0); }
        else if ((s % 3) == 1) { MFMA_STEP8(((s & 1) ? Ab1 : Ab0), Bb1); }
        else                   { MFMA_STEP8(((s & 1) ? Ab1 : Ab0), Bb2); }
    }
    __syncthreads();   // all staging reads done before repack alias

    const int proj = nt >> 1;
    const float* bias = (proj == 0) ? bq : (proj == 1) ? bk : bv;
    float bvv[2];
    #pragma unroll
    for (int g = 0; g < 2; ++g)
        bvv[g] = bias[(nt * 128 + wn * 32 + g * 16 + l15) & 255];

    // repack: q/k as [c][e], v as [e][c]
    #pragma unroll
    for (int fm = 0; fm < 4; ++fm)
        #pragma unroll
        for (int g = 0; g < 2; ++g)
            #pragma unroll
            for (int rg = 0; rg < 4; ++rg) {
                const int m = wm * 64 + fm * 16 + lhi * 4 + rg;
                const int n = wn * 32 + g * 16 + l15;
                const ushort val = f2bf(acc[fm][g][rg] + bvv[g]);
                if (proj < 2) S[m * RP + n] = val;
                else          S[n * RP + m] = val;
            }
    __syncthreads();

    const int r = rc0 >> 9, c0 = rc0 & 511;
    if (proj < 2) {
        ushort* dst = (proj == 0) ? qb : kb;
        #pragma unroll
        for (int c = 0; c < 4; ++c) {
            const int idx = t + 512 * c;
            const int mrow = idx >> 4, ne = (idx & 15) * 8;
            uint4 w = *(const uint4*)(S + mrow * RP + ne);
            if (proj == 0) {   // q: * 1/128 * (1-mask)
                const float sk = 0.0078125f * (1.0f - mask[rc0 + mrow]);
                ushort* ws = (ushort*)&w;
                #pragma unroll
                for (int jj = 0; jj < 8; ++jj) ws[jj] = f2bf(bf2f(ws[jj]) * sk);
            }
            const int e = (nt & 1) * 128 + ne, h = e >> 5, d = e & 31;
            *(uint4*)(dst + ((((size_t)h * R_ + r) * C_) + c0 + mrow) * D_ + d) = w;
        }
    } else {
        #pragma unroll
        for (int c = 0; c < 4; ++c) {
            const int idx = t + 512 * c;
            const int nrow = idx >> 4, m0 = (idx & 15) * 8;
            uint4 w = *(const uint4*)(S + nrow * RP + m0);
            const int e = (nt & 1) * 128 + nrow, h = e >> 5, d = e & 31;
            *(uint4*)(vb + (((size_t)h * R_ + r) * D_ + d) * C_ + c0 + m0) = w;
        }
    }
#undef ALOAD0
#undef ALOAD1
#undef AWRITE0
#undef AWRITE1
#undef BGLL
}

// ---------------------------------------------------------------------------
// Attention logits.  128x128 tile, 512 threads (8 waves 2x4), K split 8-way.
// ---------------------------------------------------------------------------
__global__ __launch_bounds__(512) void logits_mfma(
    const ushort* __restrict__ qb, const ushort* __restrict__ kb,
    float* __restrict__ partial)
{
    __shared__ __align__(16) ushort S[24576];
    BUFS3;
    const int id = ((blockIdx.x & 7) * 128) + (blockIdx.x >> 3);
    const int sub = id & 15;
    const int j0 = (sub & 3) * 128;         // j fastest: 4 blocks share q panel
    const int i0 = (sub >> 2) * 128;
    const int hks = id >> 4;                // 0..63
    const int h = hks >> 3, ks = hks & 7;
    PREAMBLE8;

    const ushort* Ab = qb + (((size_t)h * R_ + ks * 64) * C_ + i0) * D_;
    const ushort* Bb = kb + (((size_t)h * R_ + ks * 64) * C_ + j0) * D_;

#define LSTG(i, Abuf, Bbuf) {                                   \
    const ushort* Ai = Ab + (size_t)(i) * (C_ * D_);            \
    const ushort* Bi = Bb + (size_t)(i) * (C_ * D_);            \
    SCH(Ai, D_, Abuf, t); SCH(Bi, D_, Bbuf, t); }
    DBUFT8(LSTG, 64);

    float* dst = partial + ((size_t)ks * H_ + h) * C_ * C_;
    #pragma unroll
    for (int fm = 0; fm < 4; ++fm)
        #pragma unroll
        for (int rg = 0; rg < 4; ++rg) {
            const int i = i0 + wm * 64 + fm * 16 + lhi * 4 + rg;
            #pragma unroll
            for (int fn = 0; fn < 2; ++fn) {
                const int j = j0 + wn * 32 + fn * 16 + l15;
                dst[(size_t)i * C_ + j] = acc[fm][fn][rg];
            }
        }
}

// ---------------------------------------------------------------------------
// Sum 8 K-split partials + i-axis mask + softmax over j.
// ---------------------------------------------------------------------------
__global__ __launch_bounds__(256) void softmax_kernel(
    const float* __restrict__ partial, const float* __restrict__ mask,
    float* __restrict__ probs, ushort* __restrict__ Pb)
{
    const int hi = blockIdx.x;
    const int i = hi & 511;
    const int t = threadIdx.x;
    const size_t base = (size_t)hi * C_;
    const size_t stride = (size_t)H_ * C_ * C_;
    float v0 = 0.f, v1 = 0.f;
    #pragma unroll
    for (int ksp = 0; ksp < 8; ++ksp) {
        v0 += partial[ksp * stride + base + t];
        v1 += partial[ksp * stride + base + t + 256];
    }
    const float mi = mask[i];
    const float keep = 1.0f - mi;
    v0 = v0 * keep + mi * (-10000.0f);
    v1 = v1 * keep + mi * (-10000.0f);

    float m = fmaxf(v0, v1);
    #pragma unroll
    for (int off = 32; off > 0; off >>= 1) m = fmaxf(m, __shfl_xor(m, off));
    __shared__ float red[4];
    if ((t & 63) == 0) red[t >> 6] = m;
    __syncthreads();
    m = fmaxf(fmaxf(red[0], red[1]), fmaxf(red[2], red[3]));

    const float e0 = expf(v0 - m), e1 = expf(v1 - m);
    float s = e0 + e1;
    #pragma unroll
    for (int off = 32; off > 0; off >>= 1) s += __shfl_xor(s, off);
    __syncthreads();
    if ((t & 63) == 0) red[t >> 6] = s;
    __syncthreads();
    s = red[0] + red[1] + red[2] + red[3];

    const float inv = 1.0f / s;
    const float p0 = e0 * inv, p1 = e1 * inv;
    probs[base + t] = p0;
    probs[base + t + 256] = p1;
    Pb[base + t] = f2bf(p0);
    Pb[base + t + 256] = f2bf(p1);
}

// ---------------------------------------------------------------------------
// Context.  128x128 tile, 512 threads (8 waves 2x4), 4096 blocks.
// ---------------------------------------------------------------------------
__global__ __launch_bounds__(512) void context_mfma(
    const ushort* __restrict__ Pb, const ushort* __restrict__ vb,
    ushort* __restrict__ ctxb)
{
    __shared__ __align__(16) ushort S[24576];
    BUFS3;
    const int id = ((blockIdx.x & 7) * 512) + (blockIdx.x >> 3);
    const int i0 = (id & 3) * 128;          // i fastest: 4 blocks share vb panel
    const int n0 = ((id >> 2) & 127) * 128;
    const int h = id >> 9;
    PREAMBLE8;

    const ushort* Ab = Pb + ((size_t)h * C_ + i0) * C_;
    const ushort* Bb = vb + ((size_t)h * R_ * D_ + n0) * C_;

#define CSTG(i, Abuf, Bbuf) {                                   \
    const ushort* Ai = Ab + (i) * 32;                           \
    const ushort* Bi = Bb + (i) * 32;                           \
    SCH(Ai, C_, Abuf, t); SCH(Bi, C_, Bbuf, t); }
    DBUFT8(CSTG, 16);
    __syncthreads();   // staging reads done before repack alias

    #pragma unroll
    for (int fm = 0; fm < 4; ++fm)
        #pragma unroll
        for (int fn = 0; fn < 2; ++fn)
            #pragma unroll
            for (int rg = 0; rg < 4; ++rg) {
                const int m = wm * 64 + fm * 16 + lhi * 4 + rg;
                const int n = wn * 32 + fn * 16 + l15;
                S[m * RP + n] = f2bf(acc[fm][fn][rg]);
            }
    __syncthreads();

    #pragma unroll
    for (int c = 0; c < 4; ++c) {
        const int idx = t + 512 * c;
        const int mrow = idx >> 4, nl = (idx & 15) * 8;
        uint4 w = *(const uint4*)(S + mrow * RP + nl);
        const int n = n0 + nl;
        const int rr = n >> 5, d = n & 31;
        const size_t rc = (size_t)rr * C_ + i0 + mrow;
        *(uint4*)(ctxb + rc * E_ + h * D_ + d) = w;
    }
}

// ---------------------------------------------------------------------------
// Output projection.  128x128 tile, 512 threads (8 waves 2x4), fp32 out.
// 2-phase Sf repack: phase p handled by waves with (wn>>1)==p; local col
// s = (wn&1)*32 + g*16 + l15 -> global ncol = n0 + p*64 + s (linear).
// ---------------------------------------------------------------------------
__global__ __launch_bounds__(512) void out_proj_mfma(
    const ushort* __restrict__ ctxb, const ushort* __restrict__ WoT,
    const float* __restrict__ bo, float* __restrict__ out)
{
    __shared__ __align__(16) ushort S[24576];
    BUFS3;
    float* Sf = (float*)S;                  // 128 x 68 fp32 repack (aliases)
    const int id = ((blockIdx.x & 7) * 512) + (blockIdx.x >> 3);
    const int n0 = (id & 1) * 128;
    const int rc0 = (id >> 1) * 128;
    PREAMBLE8;

    const ushort* Ab = ctxb + (size_t)rc0 * E_;
    const ushort* Bb = WoT + (size_t)n0 * E_;

#define OSTG(i, Abuf, Bbuf) {                                   \
    const ushort* Ai = Ab + (i) * 32;                           \
    const ushort* Bi = Bb + (i) * 32;                           \
    SCH(Ai, E_, Abuf, t); SCH(Bi, E_, Bbuf, t); }
    DBUFT8(OSTG, 8);
    __syncthreads();   // staging reads done before repack alias

    float bvv[2];
    #pragma unroll
    for (int g = 0; g < 2; ++g)
        bvv[g] = bo[n0 + wn * 32 + g * 16 + l15];

    #pragma unroll
    for (int p = 0; p < 2; ++p) {
        if ((wn >> 1) == p) {
            #pragma unroll
            for (int fm = 0; fm < 4; ++fm)
                #pragma unroll
                for (int g = 0; g < 2; ++g)
                    #pragma unroll
                    for (int rg = 0; rg < 4; ++rg) {
                        const int m = wm * 64 + fm * 16 + lhi * 4 + rg;
                        const int s = (wn & 1) * 32 + g * 16 + l15;
                        Sf[m * 68 + s] = acc[fm][g][rg] + bvv[g];
                    }
        }
        __syncthreads();
        #pragma unroll
        for (int c = 0; c < 4; ++c) {
            const int idx = t + 512 * c;
            const int row = idx >> 4, s0 = (idx & 15) * 4;
            float4 w = *(const float4*)(Sf + row * 68 + s0);
            const int ncol = n0 + p * 64 + s0;
            *(float4*)(out + ((size_t)rc0 + row) * E_ + ncol) = w;
        }
        __syncthreads();
    }
}

// ---------------------------------------------------------------------------
extern "C" void kernel_launch(void* const* d_in, const int* in_sizes, int n_in,
                              void* d_out, int out_size, void* d_ws, size_t ws_size,
                              hipStream_t stream)
{
    const float* x    = (const float*)d_in[0];
    const float* mask = (const float*)d_in[1];
    const float* Wq   = (const float*)d_in[2];
    const float* bq   = (const float*)d_in[3];
    const float* Wk   = (const float*)d_in[4];
    const float* bk   = (const float*)d_in[5];
    const float* Wv   = (const float*)d_in[6];
    const float* bv   = (const float*)d_in[7];
    const float* Wo   = (const float*)d_in[8];
    const float* bo   = (const float*)d_in[9];

    float* out   = (float*)d_out;                       // [R,C,E] fp32
    float* probs = out + (size_t)RC_ * E_;              // [H,C,C] fp32

    char* ws = (char*)d_ws;
    ushort* qb      = (ushort*)(ws);                    // 128 MB  [h][r][c][d]
    ushort* kb      = (ushort*)(ws + 134217728ull);     // 128 MB  [h][r][c][d]
    ushort* vb      = (ushort*)(ws + 268435456ull);     // 128 MB  [h][r][d][c]
    ushort* ctxb    = (ushort*)(ws + 402653184ull);     // 128 MB  [rc][e]
    float*  partial = (float*)(ws + 536870912ull);      // 64 MB   [8][h][i][j]
    ushort* Pb      = (ushort*)(ws + 603979776ull);     // 4 MB    [h][i][j]
    ushort* WTqkv   = (ushort*)(ws + 608174080ull);     // 384 KB
    ushort* WoT     = (ushort*)(ws + 608567296ull);     // 128 KB

    convert_w<<<1024, 256, 0, stream>>>(Wq, Wk, Wv, Wo, WTqkv, WoT);
    qkv_mfma<<<12288, 512, 0, stream>>>(x, WTqkv, bq, bk, bv, mask, qb, kb, vb);
    logits_mfma<<<1024, 512, 0, stream>>>(qb, kb, partial);
    softmax_kernel<<<4096, 256, 0, stream>>>(partial, mask, probs, Pb);
    context_mfma<<<4096, 512, 0, stream>>>(Pb, vb, ctxb);
    out_proj_mfma<<<4096, 512, 0, stream>>>(ctxb, WoT, bo, out);
}

// Round 18
// 575.762 us; speedup vs baseline: 1.0171x; 1.0171x over previous
//
#include <hip/hip_runtime.h>
#include <math.h>

#define R_ 512
#define C_ 512
#define E_ 256
#define H_ 8
#define D_ 32
#define RC_ (R_*C_)   // 262144
#define RP 136        // repack pitch (ushorts)

typedef __attribute__((ext_vector_type(8))) short bf16x8;
typedef __attribute__((ext_vector_type(4))) float f32x4;

__device__ __forceinline__ ushort f2bf(float f) {
    union { float f; unsigned u; } v; v.f = f;
    unsigned r = v.u + 0x7FFFu + ((v.u >> 16) & 1u);   // RNE
    return (ushort)(r >> 16);
}
__device__ __forceinline__ float bf2f(ushort u) {
    union { unsigned u; float f; } v; v.u = ((unsigned)u) << 16;
    return v.f;
}
// packed f32x2 -> bf16x2 (RNE on gfx950)
__device__ __forceinline__ unsigned cvtpk(float lo, float hi) {
    unsigned r;
    asm("v_cvt_pk_bf16_f32 %0, %1, %2" : "=v"(r) : "v"(lo), "v"(hi));
    return r;
}

// 16B global->LDS direct copy (lane-linear dest), fallback = reg staging.
__device__ __forceinline__ void gll16(const ushort* g, ushort* l) {
#if __has_builtin(__builtin_amdgcn_global_load_lds)
    __builtin_amdgcn_global_load_lds(
        (const __attribute__((address_space(1))) unsigned*)(unsigned long long)g,
        (__attribute__((address_space(3))) unsigned*)(unsigned)(unsigned long long)l,
        16, 0, 0);
#else
    *(uint4*)l = *(const uint4*)g;
#endif
}

// Stage one 16B chunk f of a [rows][32-ushort] bf16 tile.  Source slot
// XOR-swizzled with (row>>1)&3 (r12-proven key).  LDS dest lane-linear.
#define SCH(gbase, stride, lds, f)                                               \
    gll16((gbase) + (size_t)((f) >> 2) * (stride)                                \
              + (((((f) & 3) ^ ((((f) >> 2) >> 1) & 3))) << 3),                  \
          (lds) + (f) * 8)

// --- Fenced sync primitives (validated r11/r12: rule #18 double-fence).
#define SCHED0   __builtin_amdgcn_sched_barrier(0)
#define ABAR     __builtin_amdgcn_s_barrier()
#define VMCNT(N) asm volatile("s_waitcnt vmcnt(" #N ")" ::: "memory")
#define LGKM0    asm volatile("s_waitcnt lgkmcnt(0)" ::: "memory")

// Per-wave 64x64 output, 16x16x32 bf16 MFMA, K=32 per step, 32-ushort rows.
#define PREAMBLE(WM, WN)                                \
    const int t = threadIdx.x;                          \
    const int wid = t >> 6, l = t & 63;                 \
    const int wm = (WM), wn = (WN);                     \
    const int l15 = l & 15, lhi = l >> 4;               \
    const int swz8 = (lhi ^ ((l15 >> 1) & 3)) * 8;      \
    f32x4 acc[4][4];                                    \
    _Pragma("unroll")                                   \
    for (int a_ = 0; a_ < 4; ++a_)                      \
        _Pragma("unroll")                               \
        for (int b_ = 0; b_ < 4; ++b_)                  \
            acc[a_][b_] = (f32x4){0.f, 0.f, 0.f, 0.f};

#define MFMA_STEP(As, Bs)                                                        \
    {                                                                            \
        bf16x8 af_[4], bf_[4];                                                   \
        _Pragma("unroll")                                                        \
        for (int f_ = 0; f_ < 4; ++f_) {                                         \
            af_[f_] = *(const bf16x8*)((As) + (wm*64 + f_*16 + l15)*32 + swz8);  \
            bf_[f_] = *(const bf16x8*)((Bs) + (wn*64 + f_*16 + l15)*32 + swz8);  \
        }                                                                        \
        _Pragma("unroll")                                                        \
        for (int m_ = 0; m_ < 4; ++m_)                                           \
            _Pragma("unroll")                                                    \
            for (int n_ = 0; n_ < 4; ++n_)                                       \
                acc[m_][n_] = __builtin_amdgcn_mfma_f32_16x16x32_bf16(           \
                    af_[m_], bf_[n_], acc[m_][n_], 0, 0, 0);                     \
    }

// Triple-buffered K-loop, ONE fenced barrier per step, prefetch distance 2
// (validated r12).  Requires A0..A2/B0..B2; each STG = 4 gll16/thread.
#define DBUFT(STG, NIT)                                                          \
    STG(0, A0, B0); STG(1, A1, B1);                                              \
    _Pragma("unroll")                                                            \
    for (int s = 0; s < (NIT); ++s) {                                            \
        if (s < (NIT) - 1) { VMCNT(4); } else { VMCNT(0); }                      \
        SCHED0; ABAR; SCHED0;                                                    \
        if (s + 2 < (NIT)) {                                                     \
            if (((s + 2) % 3) == 0)      { STG(s + 2, A0, B0); }                 \
            else if (((s + 2) % 3) == 1) { STG(s + 2, A1, B1); }                 \
            else                         { STG(s + 2, A2, B2); }                 \
        }                                                                        \
        if ((s % 3) == 0)      { MFMA_STEP(A0, B0); }                            \
        else if ((s % 3) == 1) { MFMA_STEP(A1, B1); }                            \
        else                   { MFMA_STEP(A2, B2); }                            \
    }

#define BUFS3 ushort* A0 = S;          ushort* B0 = S + 4096;                    \
              ushort* A1 = S + 8192;   ushort* B1 = S + 12288;                   \
              ushort* A2 = S + 16384;  ushort* B2 = S + 20480;

// ---------------------------------------------------------------------------
// Weights -> n-major bf16.
// ---------------------------------------------------------------------------
__global__ __launch_bounds__(256) void convert_w(
    const float* __restrict__ Wq, const float* __restrict__ Wk,
    const float* __restrict__ Wv, const float* __restrict__ Wo,
    ushort* __restrict__ WTqkv, ushort* __restrict__ WoT)
{
    const int id = blockIdx.x;      // 0..1023
    const int matn = id >> 8;
    const int n = id & 255;
    const int k = threadIdx.x;
    const float* W = (matn == 0) ? Wq : (matn == 1) ? Wk : (matn == 2) ? Wv : Wo;
    ushort v = f2bf(W[(size_t)k * E_ + n]);
    if (matn < 3) WTqkv[((size_t)matn * E_ + n) * E_ + k] = v;
    else          WoT[(size_t)n * E_ + k] = v;
}

// ---------------------------------------------------------------------------
// Fused QKV projection: 512 threads (8 waves 2x4), 128x128 tile.  Fenced
// reg-staged schedule (r16, measured best): 2 A float4 + 1 B gll per thread,
// VMCNT(3); LDS 40KB -> 4 blocks/CU x 8 waves = 64% occupancy.
// ---------------------------------------------------------------------------
__global__ __launch_bounds__(512) void qkv_mfma(
    const float* __restrict__ x, const ushort* __restrict__ WT,
    const float* __restrict__ bq, const float* __restrict__ bk,
    const float* __restrict__ bv, const float* __restrict__ mask,
    ushort* __restrict__ qb, ushort* __restrict__ kb, ushort* __restrict__ vb)
{
    __shared__ __align__(16) ushort S[20480];   // 40KB; repack aliases front
    ushort* Ab0 = S;            // bf16 [128][32]
    ushort* Ab1 = S + 4096;
    ushort* Bb0 = S + 8192;
    ushort* Bb1 = S + 12288;
    ushort* Bb2 = S + 16384;
    const int id = ((blockIdx.x & 7) * 1536) + (blockIdx.x >> 3);
    const int nt = id % 6;
    const int rc0 = (id / 6) * 128;
    const int t = threadIdx.x;
    const int wid = t >> 6, l = t & 63;
    const int wm = wid >> 2, wn = wid & 3;   // 2 x 4 waves: 64m x 32n each
    const int l15 = l & 15, lhi = l >> 4;
    const int swz8 = (lhi ^ ((l15 >> 1) & 3)) * 8;
    f32x4 acc[4][2];
    #pragma unroll
    for (int a_ = 0; a_ < 4; ++a_)
        #pragma unroll
        for (int b_ = 0; b_ < 2; ++b_)
            acc[a_][b_] = (f32x4){0.f, 0.f, 0.f, 0.f};

    const float*  Ag = x + (size_t)rc0 * E_;
    const ushort* Bg = WT + (size_t)nt * 128 * E_;

    // A: thread t owns one bf16 16B chunk: row = t>>2 (0..127), slot = t&3;
    // source fp32 chunk cc = slot ^ ((row>>1)&3) (r12 key).
    const int rowA = t >> 2;
    const int ccA = (t & 3) ^ ((rowA >> 1) & 3);
    const float* Ap = Ag + (size_t)rowA * E_ + ccA * 8;
    const int wsA = rowA * 32 + (t & 3) * 8;

    float4 rA0a, rA0b;   // reg set 0 (even steps)
    float4 rA1a, rA1b;   // reg set 1 (odd steps)

#define ALOAD0(i) { rA0a = *(const float4*)(Ap + (i)*32);                        \
                    rA0b = *(const float4*)(Ap + (i)*32 + 4); }
#define ALOAD1(i) { rA1a = *(const float4*)(Ap + (i)*32);                        \
                    rA1b = *(const float4*)(Ap + (i)*32 + 4); }
#define AWRITE0(buf) { uint4 w_ = { cvtpk(rA0a.x,rA0a.y), cvtpk(rA0a.z,rA0a.w),  \
                                    cvtpk(rA0b.x,rA0b.y), cvtpk(rA0b.z,rA0b.w)}; \
                       *(uint4*)((buf) + wsA) = w_; }
#define AWRITE1(buf) { uint4 w_ = { cvtpk(rA1a.x,rA1a.y), cvtpk(rA1a.z,rA1a.w),  \
                                    cvtpk(rA1b.x,rA1b.y), cvtpk(rA1b.z,rA1b.w)}; \
                       *(uint4*)((buf) + wsA) = w_; }
#define BGLL(i, buf) { const ushort* Bi_ = Bg + (i) * 32;                        \
                       SCH(Bi_, E_, buf, t); }
#define QMFMA(As, Bs) {                                                          \
    bf16x8 af_[4], bf_[2];                                                       \
    _Pragma("unroll")                                                            \
    for (int f_ = 0; f_ < 4; ++f_)                                               \
        af_[f_] = *(const bf16x8*)((As) + (wm*64 + f_*16 + l15)*32 + swz8);      \
    _Pragma("unroll")                                                            \
    for (int g_ = 0; g_ < 2; ++g_)                                               \
        bf_[g_] = *(const bf16x8*)((Bs) + (wn*32 + g_*16 + l15)*32 + swz8);      \
    _Pragma("unroll")                                                            \
    for (int m_ = 0; m_ < 4; ++m_)                                               \
        _Pragma("unroll")                                                        \
        for (int n_ = 0; n_ < 2; ++n_)                                           \
            acc[m_][n_] = __builtin_amdgcn_mfma_f32_16x16x32_bf16(               \
                af_[m_], bf_[n_], acc[m_][n_], 0, 0, 0); }

    // Prologue: batches 0 and 1 (each = 2 A float4 loads + 1 B gll).
    ALOAD0(0); BGLL(0, Bb0);
    ALOAD1(1); BGLL(1, Bb1);

    #pragma unroll
    for (int s = 0; s < 8; ++s) {
        if (s < 7) { VMCNT(3); } else { VMCNT(0); }   // batch s landed
        SCHED0;
        if ((s & 1) == 0) { AWRITE0((s & 1) ? Ab1 : Ab0); }
        else              { AWRITE1((s & 1) ? Ab1 : Ab0); }
        LGKM0; SCHED0; ABAR; SCHED0;
        if (s + 2 < 8) {
            if ((s & 1) == 0) { ALOAD0(s + 2); }       // reuse set s&1
            else              { ALOAD1(s + 2); }
            if (((s + 2) % 3) == 0)      { BGLL(s + 2, Bb0); }
            else if (((s + 2) % 3) == 1) { BGLL(s + 2, Bb1); }
            else                         { BGLL(s + 2, Bb2); }
        }
        if ((s % 3) == 0)      { QMFMA(((s & 1) ? Ab1 : Ab0), Bb0); }
        else if ((s % 3) == 1) { QMFMA(((s & 1) ? Ab1 : Ab0), Bb1); }
        else                   { QMFMA(((s & 1) ? Ab1 : Ab0), Bb2); }
    }
    __syncthreads();   // all staging reads done before repack alias

    const int proj = nt >> 1;
    const float* bias = (proj == 0) ? bq : (proj == 1) ? bk : bv;
    float bvv[2];
    #pragma unroll
    for (int g = 0; g < 2; ++g)
        bvv[g] = bias[(nt * 128 + wn * 32 + g * 16 + l15) & 255];

    // repack: q/k as [c][e], v as [e][c]
    #pragma unroll
    for (int fm = 0; fm < 4; ++fm)
        #pragma unroll
        for (int g = 0; g < 2; ++g)
            #pragma unroll
            for (int rg = 0; rg < 4; ++rg) {
                const int m = wm * 64 + fm * 16 + lhi * 4 + rg;
                const int n = wn * 32 + g * 16 + l15;
                const ushort val = f2bf(acc[fm][g][rg] + bvv[g]);
                if (proj < 2) S[m * RP + n] = val;
                else          S[n * RP + m] = val;
            }
    __syncthreads();

    const int r = rc0 >> 9, c0 = rc0 & 511;
    if (proj < 2) {
        ushort* dst = (proj == 0) ? qb : kb;
        #pragma unroll
        for (int c = 0; c < 4; ++c) {
            const int idx = t + 512 * c;
            const int mrow = idx >> 4, ne = (idx & 15) * 8;
            uint4 w = *(const uint4*)(S + mrow * RP + ne);
            if (proj == 0) {   // q: * 1/128 * (1-mask)
                const float sk = 0.0078125f * (1.0f - mask[rc0 + mrow]);
                ushort* ws = (ushort*)&w;
                #pragma unroll
                for (int jj = 0; jj < 8; ++jj) ws[jj] = f2bf(bf2f(ws[jj]) * sk);
            }
            const int e = (nt & 1) * 128 + ne, h = e >> 5, d = e & 31;
            *(uint4*)(dst + ((((size_t)h * R_ + r) * C_) + c0 + mrow) * D_ + d) = w;
        }
    } else {
        #pragma unroll
        for (int c = 0; c < 4; ++c) {
            const int idx = t + 512 * c;
            const int nrow = idx >> 4, m0 = (idx & 15) * 8;
            uint4 w = *(const uint4*)(S + nrow * RP + m0);
            const int e = (nt & 1) * 128 + nrow, h = e >> 5, d = e & 31;
            *(uint4*)(vb + (((size_t)h * R_ + r) * D_ + d) * C_ + c0 + m0) = w;
        }
    }
#undef ALOAD0
#undef ALOAD1
#undef AWRITE0
#undef AWRITE1
#undef BGLL
#undef QMFMA
}

// ---------------------------------------------------------------------------
// Attention logits.  128x128 tile, 256 threads, K split 8-way (1024 blocks).
// ---------------------------------------------------------------------------
__global__ __launch_bounds__(256) void logits_mfma(
    const ushort* __restrict__ qb, const ushort* __restrict__ kb,
    float* __restrict__ partial)
{
    __shared__ __align__(16) ushort S[24576];
    BUFS3;
    const int id = ((blockIdx.x & 7) * 128) + (blockIdx.x >> 3);
    const int sub = id & 15;
    const int j0 = (sub & 3) * 128;         // j fastest: 4 blocks share q panel
    const int i0 = (sub >> 2) * 128;
    const int hks = id >> 4;                // 0..63
    const int h = hks >> 3, ks = hks & 7;
    PREAMBLE(wid >> 1, wid & 1);

    const ushort* Ab = qb + (((size_t)h * R_ + ks * 64) * C_ + i0) * D_;
    const ushort* Bb = kb + (((size_t)h * R_ + ks * 64) * C_ + j0) * D_;

#define LSTG(i, Abuf, Bbuf) {                                   \
    const ushort* Ai = Ab + (size_t)(i) * (C_ * D_);            \
    const ushort* Bi = Bb + (size_t)(i) * (C_ * D_);            \
    SCH(Ai, D_, Abuf, t); SCH(Ai, D_, Abuf, t + 256);           \
    SCH(Bi, D_, Bbuf, t); SCH(Bi, D_, Bbuf, t + 256); }
    DBUFT(LSTG, 64);

    float* dst = partial + ((size_t)ks * H_ + h) * C_ * C_;
    #pragma unroll
    for (int fm = 0; fm < 4; ++fm)
        #pragma unroll
        for (int rg = 0; rg < 4; ++rg) {
            const int i = i0 + wm * 64 + fm * 16 + lhi * 4 + rg;
            #pragma unroll
            for (int fn = 0; fn < 4; ++fn) {
                const int j = j0 + wn * 64 + fn * 16 + l15;
                dst[(size_t)i * C_ + j] = acc[fm][fn][rg];
            }
        }
}

// ---------------------------------------------------------------------------
// Sum 8 K-split partials + i-axis mask + softmax over j.
// ---------------------------------------------------------------------------
__global__ __launch_bounds__(256) void softmax_kernel(
    const float* __restrict__ partial, const float* __restrict__ mask,
    float* __restrict__ probs, ushort* __restrict__ Pb)
{
    const int hi = blockIdx.x;
    const int i = hi & 511;
    const int t = threadIdx.x;
    const size_t base = (size_t)hi * C_;
    const size_t stride = (size_t)H_ * C_ * C_;
    float v0 = 0.f, v1 = 0.f;
    #pragma unroll
    for (int ksp = 0; ksp < 8; ++ksp) {
        v0 += partial[ksp * stride + base + t];
        v1 += partial[ksp * stride + base + t + 256];
    }
    const float mi = mask[i];
    const float keep = 1.0f - mi;
    v0 = v0 * keep + mi * (-10000.0f);
    v1 = v1 * keep + mi * (-10000.0f);

    float m = fmaxf(v0, v1);
    #pragma unroll
    for (int off = 32; off > 0; off >>= 1) m = fmaxf(m, __shfl_xor(m, off));
    __shared__ float red[4];
    if ((t & 63) == 0) red[t >> 6] = m;
    __syncthreads();
    m = fmaxf(fmaxf(red[0], red[1]), fmaxf(red[2], red[3]));

    const float e0 = expf(v0 - m), e1 = expf(v1 - m);
    float s = e0 + e1;
    #pragma unroll
    for (int off = 32; off > 0; off >>= 1) s += __shfl_xor(s, off);
    __syncthreads();
    if ((t & 63) == 0) red[t >> 6] = s;
    __syncthreads();
    s = red[0] + red[1] + red[2] + red[3];

    const float inv = 1.0f / s;
    const float p0 = e0 * inv, p1 = e1 * inv;
    probs[base + t] = p0;
    probs[base + t + 256] = p1;
    Pb[base + t] = f2bf(p0);
    Pb[base + t + 256] = f2bf(p1);
}

// ---------------------------------------------------------------------------
// Context.  128x128 tile, 256 threads, 4096 blocks (one head per XCD).
// ---------------------------------------------------------------------------
__global__ __launch_bounds__(256) void context_mfma(
    const ushort* __restrict__ Pb, const ushort* __restrict__ vb,
    ushort* __restrict__ ctxb)
{
    __shared__ __align__(16) ushort S[24576];
    BUFS3;
    const int id = ((blockIdx.x & 7) * 512) + (blockIdx.x >> 3);
    const int i0 = (id & 3) * 128;          // i fastest: 4 blocks share vb panel
    const int n0 = ((id >> 2) & 127) * 128;
    const int h = id >> 9;
    PREAMBLE(wid >> 1, wid & 1);

    const ushort* Ab = Pb + ((size_t)h * C_ + i0) * C_;
    const ushort* Bb = vb + ((size_t)h * R_ * D_ + n0) * C_;

#define CSTG(i, Abuf, Bbuf) {                                   \
    const ushort* Ai = Ab + (i) * 32;                           \
    const ushort* Bi = Bb + (i) * 32;                           \
    SCH(Ai, C_, Abuf, t); SCH(Ai, C_, Abuf, t + 256);           \
    SCH(Bi, C_, Bbuf, t); SCH(Bi, C_, Bbuf, t + 256); }
    DBUFT(CSTG, 16);
    __syncthreads();   // staging reads done before repack alias

    #pragma unroll
    for (int fm = 0; fm < 4; ++fm)
        #pragma unroll
        for (int fn = 0; fn < 4; ++fn)
            #pragma unroll
            for (int rg = 0; rg < 4; ++rg) {
                const int m = wm * 64 + fm * 16 + lhi * 4 + rg;
                const int n = wn * 64 + fn * 16 + l15;
                S[m * RP + n] = f2bf(acc[fm][fn][rg]);
            }
    __syncthreads();

    #pragma unroll
    for (int c = 0; c < 8; ++c) {
        const int idx = t + 256 * c;
        const int mrow = idx >> 4, nl = (idx & 15) * 8;
        uint4 w = *(const uint4*)(S + mrow * RP + nl);
        const int n = n0 + nl;
        const int rr = n >> 5, d = n & 31;
        const size_t rc = (size_t)rr * C_ + i0 + mrow;
        *(uint4*)(ctxb + rc * E_ + h * D_ + d) = w;
    }
}

// ---------------------------------------------------------------------------
// Output projection.  128x128 tile, 256 threads, 4096 blocks, fp32 out.
// ---------------------------------------------------------------------------
__global__ __launch_bounds__(256) void out_proj_mfma(
    const ushort* __restrict__ ctxb, const ushort* __restrict__ WoT,
    const float* __restrict__ bo, float* __restrict__ out)
{
    __shared__ __align__(16) ushort S[24576];
    BUFS3;
    float* Sf = (float*)S;                  // 128 x 68 fp32 repack (aliases)
    const int id = ((blockIdx.x & 7) * 512) + (blockIdx.x >> 3);
    const int n0 = (id & 1) * 128;
    const int rc0 = (id >> 1) * 128;
    PREAMBLE(wid >> 1, wid & 1);

    const ushort* Ab = ctxb + (size_t)rc0 * E_;
    const ushort* Bb = WoT + (size_t)n0 * E_;

#define OSTG(i, Abuf, Bbuf) {                                   \
    const ushort* Ai = Ab + (i) * 32;                           \
    const ushort* Bi = Bb + (i) * 32;                           \
    SCH(Ai, E_, Abuf, t); SCH(Ai, E_, Abuf, t + 256);           \
    SCH(Bi, E_, Bbuf, t); SCH(Bi, E_, Bbuf, t + 256); }
    DBUFT(OSTG, 8);
    __syncthreads();   // staging reads done before repack alias

    float bvv[4];
    #pragma unroll
    for (int fn = 0; fn < 4; ++fn)
        bvv[fn] = bo[n0 + wn * 64 + fn * 16 + l15];

    #pragma unroll
    for (int p = 0; p < 2; ++p) {
        #pragma unroll
        for (int fm = 0; fm < 4; ++fm)
            #pragma unroll
            for (int fh = 0; fh < 2; ++fh) {
                const int fn = 2 * p + fh;
                #pragma unroll
                for (int rg = 0; rg < 4; ++rg) {
                    const int m = wm * 64 + fm * 16 + lhi * 4 + rg;
                    const int s = wn * 32 + fh * 16 + l15;
                    Sf[m * 68 + s] = acc[fm][fn][rg] + bvv[fn];
                }
            }
        __syncthreads();
        #pragma unroll
        for (int c = 0; c < 8; ++c) {
            const int idx = t + 256 * c;
            const int row = idx >> 4, s0 = (idx & 15) * 4;
            float4 w = *(const float4*)(Sf + row * 68 + s0);
            const int ncol = n0 + (s0 >> 5) * 64 + (2 * p + ((s0 >> 4) & 1)) * 16 + (s0 & 15);
            *(float4*)(out + ((size_t)rc0 + row) * E_ + ncol) = w;
        }
        __syncthreads();
    }
}

// ---------------------------------------------------------------------------
extern "C" void kernel_launch(void* const* d_in, const int* in_sizes, int n_in,
                              void* d_out, int out_size, void* d_ws, size_t ws_size,
                              hipStream_t stream)
{
    const float* x    = (const float*)d_in[0];
    const float* mask = (const float*)d_in[1];
    const float* Wq   = (const float*)d_in[2];
    const float* bq   = (const float*)d_in[3];
    const float* Wk   = (const float*)d_in[4];
    const float* bk   = (const float*)d_in[5];
    const float* Wv   = (const float*)d_in[6];
    const float* bv   = (const float*)d_in[7];
    const float* Wo   = (const float*)d_in[8];
    const float* bo   = (const float*)d_in[9];

    float* out   = (float*)d_out;                       // [R,C,E] fp32
    float* probs = out + (size_t)RC_ * E_;              // [H,C,C] fp32

    char* ws = (char*)d_ws;
    ushort* qb      = (ushort*)(ws);                    // 128 MB  [h][r][c][d]
    ushort* kb      = (ushort*)(ws + 134217728ull);     // 128 MB  [h][r][c][d]
    ushort* vb      = (ushort*)(ws + 268435456ull);     // 128 MB  [h][r][d][c]
    ushort* ctxb    = (ushort*)(ws + 402653184ull);     // 128 MB  [rc][e]
    float*  partial = (float*)(ws + 536870912ull);      // 64 MB   [8][h][i][j]
    ushort* Pb      = (ushort*)(ws + 603979776ull);     // 4 MB    [h][i][j]
    ushort* WTqkv   = (ushort*)(ws + 608174080ull);     // 384 KB
    ushort* WoT     = (ushort*)(ws + 608567296ull);     // 128 KB

    convert_w<<<1024, 256, 0, stream>>>(Wq, Wk, Wv, Wo, WTqkv, WoT);
    qkv_mfma<<<12288, 512, 0, stream>>>(x, WTqkv, bq, bk, bv, mask, qb, kb, vb);
    logits_mfma<<<1024, 256, 0, stream>>>(qb, kb, partial);
    softmax_kernel<<<4096, 256, 0, stream>>>(partial, mask, probs, Pb);
    context_mfma<<<4096, 256, 0, stream>>>(Pb, vb, ctxb);
    out_proj_mfma<<<4096, 256, 0, stream>>>(ctxb, WoT, bo, out);
}

// Round 19
// 552.464 us; speedup vs baseline: 1.0600x; 1.0422x over previous
//
#include <hip/hip_runtime.h>
#include <math.h>

#define R_ 512
#define C_ 512
#define E_ 256
#define H_ 8
#define D_ 32
#define RC_ (R_*C_)   // 262144
#define RP 136        // repack pitch (ushorts)

typedef __attribute__((ext_vector_type(8))) short bf16x8;
typedef __attribute__((ext_vector_type(4))) float f32x4;
typedef __attribute__((ext_vector_type(4))) unsigned u32x4;

__device__ __forceinline__ ushort f2bf(float f) {
    union { float f; unsigned u; } v; v.f = f;
    unsigned r = v.u + 0x7FFFu + ((v.u >> 16) & 1u);   // RNE
    return (ushort)(r >> 16);
}
__device__ __forceinline__ float bf2f(ushort u) {
    union { unsigned u; float f; } v; v.u = ((unsigned)u) << 16;
    return v.f;
}
// packed f32x2 -> bf16x2 (RNE on gfx950)
__device__ __forceinline__ unsigned cvtpk(float lo, float hi) {
    unsigned r;
    asm("v_cvt_pk_bf16_f32 %0, %1, %2" : "=v"(r) : "v"(lo), "v"(hi));
    return r;
}
// Non-temporal 16B stores (streaming write-once data: bypass L2 retention).
__device__ __forceinline__ void nts_u4(ushort* p, uint4 v) {
    u32x4 w = {v.x, v.y, v.z, v.w};
    __builtin_nontemporal_store(w, (u32x4*)p);
}
__device__ __forceinline__ void nts_f4(float* p, float4 v) {
    f32x4 w = {v.x, v.y, v.z, v.w};
    __builtin_nontemporal_store(w, (f32x4*)p);
}

// 16B global->LDS direct copy (lane-linear dest), fallback = reg staging.
__device__ __forceinline__ void gll16(const ushort* g, ushort* l) {
#if __has_builtin(__builtin_amdgcn_global_load_lds)
    __builtin_amdgcn_global_load_lds(
        (const __attribute__((address_space(1))) unsigned*)(unsigned long long)g,
        (__attribute__((address_space(3))) unsigned*)(unsigned)(unsigned long long)l,
        16, 0, 0);
#else
    *(uint4*)l = *(const uint4*)g;
#endif
}

// Stage one 16B chunk f of a [rows][32-ushort] bf16 tile.  Source slot
// XOR-swizzled with (row>>1)&3 (r12-proven key).  LDS dest lane-linear.
#define SCH(gbase, stride, lds, f)                                               \
    gll16((gbase) + (size_t)((f) >> 2) * (stride)                                \
              + (((((f) & 3) ^ ((((f) >> 2) >> 1) & 3))) << 3),                  \
          (lds) + (f) * 8)

// --- Fenced sync primitives (validated r11/r12: rule #18 double-fence).
#define SCHED0   __builtin_amdgcn_sched_barrier(0)
#define ABAR     __builtin_amdgcn_s_barrier()
#define VMCNT(N) asm volatile("s_waitcnt vmcnt(" #N ")" ::: "memory")
#define LGKM0    asm volatile("s_waitcnt lgkmcnt(0)" ::: "memory")

// Per-wave 64x64 output, 16x16x32 bf16 MFMA, K=32 per step, 32-ushort rows.
#define PREAMBLE(WM, WN)                                \
    const int t = threadIdx.x;                          \
    const int wid = t >> 6, l = t & 63;                 \
    const int wm = (WM), wn = (WN);                     \
    const int l15 = l & 15, lhi = l >> 4;               \
    const int swz8 = (lhi ^ ((l15 >> 1) & 3)) * 8;      \
    f32x4 acc[4][4];                                    \
    _Pragma("unroll")                                   \
    for (int a_ = 0; a_ < 4; ++a_)                      \
        _Pragma("unroll")                               \
        for (int b_ = 0; b_ < 4; ++b_)                  \
            acc[a_][b_] = (f32x4){0.f, 0.f, 0.f, 0.f};

#define MFMA_STEP(As, Bs)                                                        \
    {                                                                            \
        bf16x8 af_[4], bf_[4];                                                   \
        _Pragma("unroll")                                                        \
        for (int f_ = 0; f_ < 4; ++f_) {                                         \
            af_[f_] = *(const bf16x8*)((As) + (wm*64 + f_*16 + l15)*32 + swz8);  \
            bf_[f_] = *(const bf16x8*)((Bs) + (wn*64 + f_*16 + l15)*32 + swz8);  \
        }                                                                        \
        _Pragma("unroll")                                                        \
        for (int m_ = 0; m_ < 4; ++m_)                                           \
            _Pragma("unroll")                                                    \
            for (int n_ = 0; n_ < 4; ++n_)                                       \
                acc[m_][n_] = __builtin_amdgcn_mfma_f32_16x16x32_bf16(           \
                    af_[m_], bf_[n_], acc[m_][n_], 0, 0, 0);                     \
    }

// Triple-buffered K-loop, ONE fenced barrier per step, prefetch distance 2
// (validated r12).  Requires A0..A2/B0..B2; each STG = 4 gll16/thread.
#define DBUFT(STG, NIT)                                                          \
    STG(0, A0, B0); STG(1, A1, B1);                                              \
    _Pragma("unroll")                                                            \
    for (int s = 0; s < (NIT); ++s) {                                            \
        if (s < (NIT) - 1) { VMCNT(4); } else { VMCNT(0); }                      \
        SCHED0; ABAR; SCHED0;                                                    \
        if (s + 2 < (NIT)) {                                                     \
            if (((s + 2) % 3) == 0)      { STG(s + 2, A0, B0); }                 \
            else if (((s + 2) % 3) == 1) { STG(s + 2, A1, B1); }                 \
            else                         { STG(s + 2, A2, B2); }                 \
        }                                                                        \
        if ((s % 3) == 0)      { MFMA_STEP(A0, B0); }                            \
        else if ((s % 3) == 1) { MFMA_STEP(A1, B1); }                            \
        else                   { MFMA_STEP(A2, B2); }                            \
    }

#define BUFS3 ushort* A0 = S;          ushort* B0 = S + 4096;                    \
              ushort* A1 = S + 8192;   ushort* B1 = S + 12288;                   \
              ushort* A2 = S + 16384;  ushort* B2 = S + 20480;

// ---------------------------------------------------------------------------
// Weights -> n-major bf16.
// ---------------------------------------------------------------------------
__global__ __launch_bounds__(256) void convert_w(
    const float* __restrict__ Wq, const float* __restrict__ Wk,
    const float* __restrict__ Wv, const float* __restrict__ Wo,
    ushort* __restrict__ WTqkv, ushort* __restrict__ WoT)
{
    const int id = blockIdx.x;      // 0..1023
    const int matn = id >> 8;
    const int n = id & 255;
    const int k = threadIdx.x;
    const float* W = (matn == 0) ? Wq : (matn == 1) ? Wk : (matn == 2) ? Wv : Wo;
    ushort v = f2bf(W[(size_t)k * E_ + n]);
    if (matn < 3) WTqkv[((size_t)matn * E_ + n) * E_ + k] = v;
    else          WoT[(size_t)n * E_ + k] = v;
}

// ---------------------------------------------------------------------------
// Fused QKV projection: 512 threads (8 waves 2x4), 128x128 tile.  Fenced
// reg-staged schedule (r16, measured best): 2 A float4 + 1 B gll per thread,
// VMCNT(3); LDS 40KB.  Epilogue stores are NON-TEMPORAL (q/k/v are 384MB
// write-once, re-read only after L2 eviction is inevitable).
// ---------------------------------------------------------------------------
__global__ __launch_bounds__(512) void qkv_mfma(
    const float* __restrict__ x, const ushort* __restrict__ WT,
    const float* __restrict__ bq, const float* __restrict__ bk,
    const float* __restrict__ bv, const float* __restrict__ mask,
    ushort* __restrict__ qb, ushort* __restrict__ kb, ushort* __restrict__ vb)
{
    __shared__ __align__(16) ushort S[20480];   // 40KB; repack aliases front
    ushort* Ab0 = S;            // bf16 [128][32]
    ushort* Ab1 = S + 4096;
    ushort* Bb0 = S + 8192;
    ushort* Bb1 = S + 12288;
    ushort* Bb2 = S + 16384;
    const int id = ((blockIdx.x & 7) * 1536) + (blockIdx.x >> 3);
    const int nt = id % 6;
    const int rc0 = (id / 6) * 128;
    const int t = threadIdx.x;
    const int wid = t >> 6, l = t & 63;
    const int wm = wid >> 2, wn = wid & 3;   // 2 x 4 waves: 64m x 32n each
    const int l15 = l & 15, lhi = l >> 4;
    const int swz8 = (lhi ^ ((l15 >> 1) & 3)) * 8;
    f32x4 acc[4][2];
    #pragma unroll
    for (int a_ = 0; a_ < 4; ++a_)
        #pragma unroll
        for (int b_ = 0; b_ < 2; ++b_)
            acc[a_][b_] = (f32x4){0.f, 0.f, 0.f, 0.f};

    const float*  Ag = x + (size_t)rc0 * E_;
    const ushort* Bg = WT + (size_t)nt * 128 * E_;

    // A: thread t owns one bf16 16B chunk: row = t>>2 (0..127), slot = t&3;
    // source fp32 chunk cc = slot ^ ((row>>1)&3) (r12 key).
    const int rowA = t >> 2;
    const int ccA = (t & 3) ^ ((rowA >> 1) & 3);
    const float* Ap = Ag + (size_t)rowA * E_ + ccA * 8;
    const int wsA = rowA * 32 + (t & 3) * 8;

    float4 rA0a, rA0b;   // reg set 0 (even steps)
    float4 rA1a, rA1b;   // reg set 1 (odd steps)

#define ALOAD0(i) { rA0a = *(const float4*)(Ap + (i)*32);                        \
                    rA0b = *(const float4*)(Ap + (i)*32 + 4); }
#define ALOAD1(i) { rA1a = *(const float4*)(Ap + (i)*32);                        \
                    rA1b = *(const float4*)(Ap + (i)*32 + 4); }
#define AWRITE0(buf) { uint4 w_ = { cvtpk(rA0a.x,rA0a.y), cvtpk(rA0a.z,rA0a.w),  \
                                    cvtpk(rA0b.x,rA0b.y), cvtpk(rA0b.z,rA0b.w)}; \
                       *(uint4*)((buf) + wsA) = w_; }
#define AWRITE1(buf) { uint4 w_ = { cvtpk(rA1a.x,rA1a.y), cvtpk(rA1a.z,rA1a.w),  \
                                    cvtpk(rA1b.x,rA1b.y), cvtpk(rA1b.z,rA1b.w)}; \
                       *(uint4*)((buf) + wsA) = w_; }
#define BGLL(i, buf) { const ushort* Bi_ = Bg + (i) * 32;                        \
                       SCH(Bi_, E_, buf, t); }
#define QMFMA(As, Bs) {                                                          \
    bf16x8 af_[4], bf_[2];                                                       \
    _Pragma("unroll")                                                            \
    for (int f_ = 0; f_ < 4; ++f_)                                               \
        af_[f_] = *(const bf16x8*)((As) + (wm*64 + f_*16 + l15)*32 + swz8);      \
    _Pragma("unroll")                                                            \
    for (int g_ = 0; g_ < 2; ++g_)                                               \
        bf_[g_] = *(const bf16x8*)((Bs) + (wn*32 + g_*16 + l15)*32 + swz8);      \
    _Pragma("unroll")                                                            \
    for (int m_ = 0; m_ < 4; ++m_)                                               \
        _Pragma("unroll")                                                        \
        for (int n_ = 0; n_ < 2; ++n_)                                           \
            acc[m_][n_] = __builtin_amdgcn_mfma_f32_16x16x32_bf16(               \
                af_[m_], bf_[n_], acc[m_][n_], 0, 0, 0); }

    // Prologue: batches 0 and 1 (each = 2 A float4 loads + 1 B gll).
    ALOAD0(0); BGLL(0, Bb0);
    ALOAD1(1); BGLL(1, Bb1);

    #pragma unroll
    for (int s = 0; s < 8; ++s) {
        if (s < 7) { VMCNT(3); } else { VMCNT(0); }   // batch s landed
        SCHED0;
        if ((s & 1) == 0) { AWRITE0((s & 1) ? Ab1 : Ab0); }
        else              { AWRITE1((s & 1) ? Ab1 : Ab0); }
        LGKM0; SCHED0; ABAR; SCHED0;
        if (s + 2 < 8) {
            if ((s & 1) == 0) { ALOAD0(s + 2); }       // reuse set s&1
            else              { ALOAD1(s + 2); }
            if (((s + 2) % 3) == 0)      { BGLL(s + 2, Bb0); }
            else if (((s + 2) % 3) == 1) { BGLL(s + 2, Bb1); }
            else                         { BGLL(s + 2, Bb2); }
        }
        if ((s % 3) == 0)      { QMFMA(((s & 1) ? Ab1 : Ab0), Bb0); }
        else if ((s % 3) == 1) { QMFMA(((s & 1) ? Ab1 : Ab0), Bb1); }
        else                   { QMFMA(((s & 1) ? Ab1 : Ab0), Bb2); }
    }
    __syncthreads();   // all staging reads done before repack alias

    const int proj = nt >> 1;
    const float* bias = (proj == 0) ? bq : (proj == 1) ? bk : bv;
    float bvv[2];
    #pragma unroll
    for (int g = 0; g < 2; ++g)
        bvv[g] = bias[(nt * 128 + wn * 32 + g * 16 + l15) & 255];

    // repack: q/k as [c][e], v as [e][c]
    #pragma unroll
    for (int fm = 0; fm < 4; ++fm)
        #pragma unroll
        for (int g = 0; g < 2; ++g)
            #pragma unroll
            for (int rg = 0; rg < 4; ++rg) {
                const int m = wm * 64 + fm * 16 + lhi * 4 + rg;
                const int n = wn * 32 + g * 16 + l15;
                const ushort val = f2bf(acc[fm][g][rg] + bvv[g]);
                if (proj < 2) S[m * RP + n] = val;
                else          S[n * RP + m] = val;
            }
    __syncthreads();

    const int r = rc0 >> 9, c0 = rc0 & 511;
    if (proj < 2) {
        ushort* dst = (proj == 0) ? qb : kb;
        #pragma unroll
        for (int c = 0; c < 4; ++c) {
            const int idx = t + 512 * c;
            const int mrow = idx >> 4, ne = (idx & 15) * 8;
            uint4 w = *(const uint4*)(S + mrow * RP + ne);
            if (proj == 0) {   // q: * 1/128 * (1-mask)
                const float sk = 0.0078125f * (1.0f - mask[rc0 + mrow]);
                ushort* ws = (ushort*)&w;
                #pragma unroll
                for (int jj = 0; jj < 8; ++jj) ws[jj] = f2bf(bf2f(ws[jj]) * sk);
            }
            const int e = (nt & 1) * 128 + ne, h = e >> 5, d = e & 31;
            nts_u4(dst + ((((size_t)h * R_ + r) * C_) + c0 + mrow) * D_ + d, w);
        }
    } else {
        #pragma unroll
        for (int c = 0; c < 4; ++c) {
            const int idx = t + 512 * c;
            const int nrow = idx >> 4, m0 = (idx & 15) * 8;
            uint4 w = *(const uint4*)(S + nrow * RP + m0);
            const int e = (nt & 1) * 128 + nrow, h = e >> 5, d = e & 31;
            nts_u4(vb + (((size_t)h * R_ + r) * D_ + d) * C_ + c0 + m0, w);
        }
    }
#undef ALOAD0
#undef ALOAD1
#undef AWRITE0
#undef AWRITE1
#undef BGLL
#undef QMFMA
}

// ---------------------------------------------------------------------------
// Attention logits.  128x128 tile, 256 threads, K split 8-way (1024 blocks).
// partial stores are non-temporal (written once, read once by softmax).
// ---------------------------------------------------------------------------
__global__ __launch_bounds__(256) void logits_mfma(
    const ushort* __restrict__ qb, const ushort* __restrict__ kb,
    float* __restrict__ partial)
{
    __shared__ __align__(16) ushort S[24576];
    BUFS3;
    const int id = ((blockIdx.x & 7) * 128) + (blockIdx.x >> 3);
    const int sub = id & 15;
    const int j0 = (sub & 3) * 128;         // j fastest: 4 blocks share q panel
    const int i0 = (sub >> 2) * 128;
    const int hks = id >> 4;                // 0..63
    const int h = hks >> 3, ks = hks & 7;
    PREAMBLE(wid >> 1, wid & 1);

    const ushort* Ab = qb + (((size_t)h * R_ + ks * 64) * C_ + i0) * D_;
    const ushort* Bb = kb + (((size_t)h * R_ + ks * 64) * C_ + j0) * D_;

#define LSTG(i, Abuf, Bbuf) {                                   \
    const ushort* Ai = Ab + (size_t)(i) * (C_ * D_);            \
    const ushort* Bi = Bb + (size_t)(i) * (C_ * D_);            \
    SCH(Ai, D_, Abuf, t); SCH(Ai, D_, Abuf, t + 256);           \
    SCH(Bi, D_, Bbuf, t); SCH(Bi, D_, Bbuf, t + 256); }
    DBUFT(LSTG, 64);

    float* dst = partial + ((size_t)ks * H_ + h) * C_ * C_;
    #pragma unroll
    for (int fm = 0; fm < 4; ++fm)
        #pragma unroll
        for (int rg = 0; rg < 4; ++rg) {
            const int i = i0 + wm * 64 + fm * 16 + lhi * 4 + rg;
            #pragma unroll
            for (int fn = 0; fn < 4; ++fn) {
                const int j = j0 + wn * 64 + fn * 16 + l15;
                __builtin_nontemporal_store(acc[fm][fn][rg],
                                            &dst[(size_t)i * C_ + j]);
            }
        }
}

// ---------------------------------------------------------------------------
// Sum 8 K-split partials (non-temporal loads: read-once) + i-axis mask +
// softmax over j.  probs/Pb stores non-temporal.
// ---------------------------------------------------------------------------
__global__ __launch_bounds__(256) void softmax_kernel(
    const float* __restrict__ partial, const float* __restrict__ mask,
    float* __restrict__ probs, ushort* __restrict__ Pb)
{
    const int hi = blockIdx.x;
    const int i = hi & 511;
    const int t = threadIdx.x;
    const size_t base = (size_t)hi * C_;
    const size_t stride = (size_t)H_ * C_ * C_;
    float v0 = 0.f, v1 = 0.f;
    #pragma unroll
    for (int ksp = 0; ksp < 8; ++ksp) {
        v0 += __builtin_nontemporal_load(&partial[ksp * stride + base + t]);
        v1 += __builtin_nontemporal_load(&partial[ksp * stride + base + t + 256]);
    }
    const float mi = mask[i];
    const float keep = 1.0f - mi;
    v0 = v0 * keep + mi * (-10000.0f);
    v1 = v1 * keep + mi * (-10000.0f);

    float m = fmaxf(v0, v1);
    #pragma unroll
    for (int off = 32; off > 0; off >>= 1) m = fmaxf(m, __shfl_xor(m, off));
    __shared__ float red[4];
    if ((t & 63) == 0) red[t >> 6] = m;
    __syncthreads();
    m = fmaxf(fmaxf(red[0], red[1]), fmaxf(red[2], red[3]));

    const float e0 = expf(v0 - m), e1 = expf(v1 - m);
    float s = e0 + e1;
    #pragma unroll
    for (int off = 32; off > 0; off >>= 1) s += __shfl_xor(s, off);
    __syncthreads();
    if ((t & 63) == 0) red[t >> 6] = s;
    __syncthreads();
    s = red[0] + red[1] + red[2] + red[3];

    const float inv = 1.0f / s;
    const float p0 = e0 * inv, p1 = e1 * inv;
    __builtin_nontemporal_store(p0, &probs[base + t]);
    __builtin_nontemporal_store(p1, &probs[base + t + 256]);
    Pb[base + t] = f2bf(p0);          // Pb is small (4MB) and reused -> cached
    Pb[base + t + 256] = f2bf(p1);
}

// ---------------------------------------------------------------------------
// Context.  128x128 tile, 256 threads, 4096 blocks (one head per XCD).
// ctxb stores non-temporal (128MB write-once).
// ---------------------------------------------------------------------------
__global__ __launch_bounds__(256) void context_mfma(
    const ushort* __restrict__ Pb, const ushort* __restrict__ vb,
    ushort* __restrict__ ctxb)
{
    __shared__ __align__(16) ushort S[24576];
    BUFS3;
    const int id = ((blockIdx.x & 7) * 512) + (blockIdx.x >> 3);
    const int i0 = (id & 3) * 128;          // i fastest: 4 blocks share vb panel
    const int n0 = ((id >> 2) & 127) * 128;
    const int h = id >> 9;
    PREAMBLE(wid >> 1, wid & 1);

    const ushort* Ab = Pb + ((size_t)h * C_ + i0) * C_;
    const ushort* Bb = vb + ((size_t)h * R_ * D_ + n0) * C_;

#define CSTG(i, Abuf, Bbuf) {                                   \
    const ushort* Ai = Ab + (i) * 32;                           \
    const ushort* Bi = Bb + (i) * 32;                           \
    SCH(Ai, C_, Abuf, t); SCH(Ai, C_, Abuf, t + 256);           \
    SCH(Bi, C_, Bbuf, t); SCH(Bi, C_, Bbuf, t + 256); }
    DBUFT(CSTG, 16);
    __syncthreads();   // staging reads done before repack alias

    #pragma unroll
    for (int fm = 0; fm < 4; ++fm)
        #pragma unroll
        for (int fn = 0; fn < 4; ++fn)
            #pragma unroll
            for (int rg = 0; rg < 4; ++rg) {
                const int m = wm * 64 + fm * 16 + lhi * 4 + rg;
                const int n = wn * 64 + fn * 16 + l15;
                S[m * RP + n] = f2bf(acc[fm][fn][rg]);
            }
    __syncthreads();

    #pragma unroll
    for (int c = 0; c < 8; ++c) {
        const int idx = t + 256 * c;
        const int mrow = idx >> 4, nl = (idx & 15) * 8;
        uint4 w = *(const uint4*)(S + mrow * RP + nl);
        const int n = n0 + nl;
        const int rr = n >> 5, d = n & 31;
        const size_t rc = (size_t)rr * C_ + i0 + mrow;
        nts_u4(ctxb + rc * E_ + h * D_ + d, w);
    }
}

// ---------------------------------------------------------------------------
// Output projection.  128x128 tile, 256 threads, 4096 blocks, fp32 out.
// out stores non-temporal (256MB, never re-read on device).
// ---------------------------------------------------------------------------
__global__ __launch_bounds__(256) void out_proj_mfma(
    const ushort* __restrict__ ctxb, const ushort* __restrict__ WoT,
    const float* __restrict__ bo, float* __restrict__ out)
{
    __shared__ __align__(16) ushort S[24576];
    BUFS3;
    float* Sf = (float*)S;                  // 128 x 68 fp32 repack (aliases)
    const int id = ((blockIdx.x & 7) * 512) + (blockIdx.x >> 3);
    const int n0 = (id & 1) * 128;
    const int rc0 = (id >> 1) * 128;
    PREAMBLE(wid >> 1, wid & 1);

    const ushort* Ab = ctxb + (size_t)rc0 * E_;
    const ushort* Bb = WoT + (size_t)n0 * E_;

#define OSTG(i, Abuf, Bbuf) {                                   \
    const ushort* Ai = Ab + (i) * 32;                           \
    const ushort* Bi = Bb + (i) * 32;                           \
    SCH(Ai, E_, Abuf, t); SCH(Ai, E_, Abuf, t + 256);           \
    SCH(Bi, E_, Bbuf, t); SCH(Bi, E_, Bbuf, t + 256); }
    DBUFT(OSTG, 8);
    __syncthreads();   // staging reads done before repack alias

    float bvv[4];
    #pragma unroll
    for (int fn = 0; fn < 4; ++fn)
        bvv[fn] = bo[n0 + wn * 64 + fn * 16 + l15];

    #pragma unroll
    for (int p = 0; p < 2; ++p) {
        #pragma unroll
        for (int fm = 0; fm < 4; ++fm)
            #pragma unroll
            for (int fh = 0; fh < 2; ++fh) {
                const int fn = 2 * p + fh;
                #pragma unroll
                for (int rg = 0; rg < 4; ++rg) {
                    const int m = wm * 64 + fm * 16 + lhi * 4 + rg;
                    const int s = wn * 32 + fh * 16 + l15;
                    Sf[m * 68 + s] = acc[fm][fn][rg] + bvv[fn];
                }
            }
        __syncthreads();
        #pragma unroll
        for (int c = 0; c < 8; ++c) {
            const int idx = t + 256 * c;
            const int row = idx >> 4, s0 = (idx & 15) * 4;
            float4 w = *(const float4*)(Sf + row * 68 + s0);
            const int ncol = n0 + (s0 >> 5) * 64 + (2 * p + ((s0 >> 4) & 1)) * 16 + (s0 & 15);
            nts_f4(out + ((size_t)rc0 + row) * E_ + ncol, w);
        }
        __syncthreads();
    }
}

// ---------------------------------------------------------------------------
extern "C" void kernel_launch(void* const* d_in, const int* in_sizes, int n_in,
                              void* d_out, int out_size, void* d_ws, size_t ws_size,
                              hipStream_t stream)
{
    const float* x    = (const float*)d_in[0];
    const float* mask = (const float*)d_in[1];
    const float* Wq   = (const float*)d_in[2];
    const float* bq   = (const float*)d_in[3];
    const float* Wk   = (const float*)d_in[4];
    const float* bk   = (const float*)d_in[5];
    const float* Wv   = (const float*)d_in[6];
    const float* bv   = (const float*)d_in[7];
    const float* Wo   = (const float*)d_in[8];
    const float* bo   = (const float*)d_in[9];

    float* out   = (float*)d_out;                       // [R,C,E] fp32
    float* probs = out + (size_t)RC_ * E_;              // [H,C,C] fp32

    char* ws = (char*)d_ws;
    ushort* qb      = (ushort*)(ws);                    // 128 MB  [h][r][c][d]
    ushort* kb      = (ushort*)(ws + 134217728ull);     // 128 MB  [h][r][c][d]
    ushort* vb      = (ushort*)(ws + 268435456ull);     // 128 MB  [h][r][d][c]
    ushort* ctxb    = (ushort*)(ws + 402653184ull);     // 128 MB  [rc][e]
    float*  partial = (float*)(ws + 536870912ull);      // 64 MB   [8][h][i][j]
    ushort* Pb      = (ushort*)(ws + 603979776ull);     // 4 MB    [h][i][j]
    ushort* WTqkv   = (ushort*)(ws + 608174080ull);     // 384 KB
    ushort* WoT     = (ushort*)(ws + 608567296ull);     // 128 KB

    convert_w<<<1024, 256, 0, stream>>>(Wq, Wk, Wv, Wo, WTqkv, WoT);
    qkv_mfma<<<12288, 512, 0, stream>>>(x, WTqkv, bq, bk, bv, mask, qb, kb, vb);
    logits_mfma<<<1024, 256, 0, stream>>>(qb, kb, partial);
    softmax_kernel<<<4096, 256, 0, stream>>>(partial, mask, probs, Pb);
    context_mfma<<<4096, 256, 0, stream>>>(Pb, vb, ctxb);
    out_proj_mfma<<<4096, 256, 0, stream>>>(ctxb, WoT, bo, out);
}

// Round 20
// 540.964 us; speedup vs baseline: 1.0825x; 1.0213x over previous
//
#include <hip/hip_runtime.h>
#include <math.h>

#define R_ 512
#define C_ 512
#define E_ 256
#define H_ 8
#define D_ 32
#define RC_ (R_*C_)   // 262144
#define RP 136        // repack pitch (ushorts)

typedef __attribute__((ext_vector_type(8))) short bf16x8;
typedef __attribute__((ext_vector_type(4))) float f32x4;
typedef __attribute__((ext_vector_type(4))) unsigned u32x4;

__device__ __forceinline__ ushort f2bf(float f) {
    union { float f; unsigned u; } v; v.f = f;
    unsigned r = v.u + 0x7FFFu + ((v.u >> 16) & 1u);   // RNE
    return (ushort)(r >> 16);
}
__device__ __forceinline__ float bf2f(ushort u) {
    union { unsigned u; float f; } v; v.u = ((unsigned)u) << 16;
    return v.f;
}
// packed f32x2 -> bf16x2 (RNE on gfx950)
__device__ __forceinline__ unsigned cvtpk(float lo, float hi) {
    unsigned r;
    asm("v_cvt_pk_bf16_f32 %0, %1, %2" : "=v"(r) : "v"(lo), "v"(hi));
    return r;
}
// Non-temporal 16B store (terminal / read-once data only).
__device__ __forceinline__ void nts_f4(float* p, float4 v) {
    f32x4 w = {v.x, v.y, v.z, v.w};
    __builtin_nontemporal_store(w, (f32x4*)p);
}

// 16B global->LDS direct copy (lane-linear dest), fallback = reg staging.
__device__ __forceinline__ void gll16(const ushort* g, ushort* l) {
#if __has_builtin(__builtin_amdgcn_global_load_lds)
    __builtin_amdgcn_global_load_lds(
        (const __attribute__((address_space(1))) unsigned*)(unsigned long long)g,
        (__attribute__((address_space(3))) unsigned*)(unsigned)(unsigned long long)l,
        16, 0, 0);
#else
    *(uint4*)l = *(const uint4*)g;
#endif
}

// Stage one 16B chunk f of a [rows][32-ushort] bf16 tile.  Source slot
// XOR-swizzled with (row>>1)&3 (r12-proven key).  LDS dest lane-linear.
#define SCH(gbase, stride, lds, f)                                               \
    gll16((gbase) + (size_t)((f) >> 2) * (stride)                                \
              + (((((f) & 3) ^ ((((f) >> 2) >> 1) & 3))) << 3),                  \
          (lds) + (f) * 8)

// --- Fenced sync primitives (validated r11/r12: rule #18 double-fence).
#define SCHED0   __builtin_amdgcn_sched_barrier(0)
#define ABAR     __builtin_amdgcn_s_barrier()
#define VMCNT(N) asm volatile("s_waitcnt vmcnt(" #N ")" ::: "memory")
#define LGKM0    asm volatile("s_waitcnt lgkmcnt(0)" ::: "memory")

// Per-wave 64x64 output, 16x16x32 bf16 MFMA, K=32 per step, 32-ushort rows.
#define PREAMBLE(WM, WN)                                \
    const int t = threadIdx.x;                          \
    const int wid = t >> 6, l = t & 63;                 \
    const int wm = (WM), wn = (WN);                     \
    const int l15 = l & 15, lhi = l >> 4;               \
    const int swz8 = (lhi ^ ((l15 >> 1) & 3)) * 8;      \
    f32x4 acc[4][4];                                    \
    _Pragma("unroll")                                   \
    for (int a_ = 0; a_ < 4; ++a_)                      \
        _Pragma("unroll")                               \
        for (int b_ = 0; b_ < 4; ++b_)                  \
            acc[a_][b_] = (f32x4){0.f, 0.f, 0.f, 0.f};

#define MFMA_STEP(As, Bs)                                                        \
    {                                                                            \
        bf16x8 af_[4], bf_[4];                                                   \
        _Pragma("unroll")                                                        \
        for (int f_ = 0; f_ < 4; ++f_) {                                         \
            af_[f_] = *(const bf16x8*)((As) + (wm*64 + f_*16 + l15)*32 + swz8);  \
            bf_[f_] = *(const bf16x8*)((Bs) + (wn*64 + f_*16 + l15)*32 + swz8);  \
        }                                                                        \
        _Pragma("unroll")                                                        \
        for (int m_ = 0; m_ < 4; ++m_)                                           \
            _Pragma("unroll")                                                    \
            for (int n_ = 0; n_ < 4; ++n_)                                       \
                acc[m_][n_] = __builtin_amdgcn_mfma_f32_16x16x32_bf16(           \
                    af_[m_], bf_[n_], acc[m_][n_], 0, 0, 0);                     \
    }

// Triple-buffered K-loop, ONE fenced barrier per step, prefetch distance 2
// (validated r12).  Requires A0..A2/B0..B2; each STG = 4 gll16/thread.
#define DBUFT(STG, NIT)                                                          \
    STG(0, A0, B0); STG(1, A1, B1);                                              \
    _Pragma("unroll")                                                            \
    for (int s = 0; s < (NIT); ++s) {                                            \
        if (s < (NIT) - 1) { VMCNT(4); } else { VMCNT(0); }                      \
        SCHED0; ABAR; SCHED0;                                                    \
        if (s + 2 < (NIT)) {                                                     \
            if (((s + 2) % 3) == 0)      { STG(s + 2, A0, B0); }                 \
            else if (((s + 2) % 3) == 1) { STG(s + 2, A1, B1); }                 \
            else                         { STG(s + 2, A2, B2); }                 \
        }                                                                        \
        if ((s % 3) == 0)      { MFMA_STEP(A0, B0); }                            \
        else if ((s % 3) == 1) { MFMA_STEP(A1, B1); }                            \
        else                   { MFMA_STEP(A2, B2); }                            \
    }

#define BUFS3 ushort* A0 = S;          ushort* B0 = S + 4096;                    \
              ushort* A1 = S + 8192;   ushort* B1 = S + 12288;                   \
              ushort* A2 = S + 16384;  ushort* B2 = S + 20480;

// ---------------------------------------------------------------------------
// Weights -> n-major bf16.
// ---------------------------------------------------------------------------
__global__ __launch_bounds__(256) void convert_w(
    const float* __restrict__ Wq, const float* __restrict__ Wk,
    const float* __restrict__ Wv, const float* __restrict__ Wo,
    ushort* __restrict__ WTqkv, ushort* __restrict__ WoT)
{
    const int id = blockIdx.x;      // 0..1023
    const int matn = id >> 8;
    const int n = id & 255;
    const int k = threadIdx.x;
    const float* W = (matn == 0) ? Wq : (matn == 1) ? Wk : (matn == 2) ? Wv : Wo;
    ushort v = f2bf(W[(size_t)k * E_ + n]);
    if (matn < 3) WTqkv[((size_t)matn * E_ + n) * E_ + k] = v;
    else          WoT[(size_t)n * E_ + k] = v;
}

// ---------------------------------------------------------------------------
// Fused QKV projection: 512 threads (8 waves 2x4), 128x128 tile.  Fenced
// reg-staged schedule (r16, measured best): 2 A float4 + 1 B gll per thread,
// VMCNT(3); LDS 40KB.  Epilogue stores CACHED (qb/kb/vb re-read by the next
// kernels; r19 showed NT here costs qkv +12us and forfeits LLC hits).
// ---------------------------------------------------------------------------
__global__ __launch_bounds__(512) void qkv_mfma(
    const float* __restrict__ x, const ushort* __restrict__ WT,
    const float* __restrict__ bq, const float* __restrict__ bk,
    const float* __restrict__ bv, const float* __restrict__ mask,
    ushort* __restrict__ qb, ushort* __restrict__ kb, ushort* __restrict__ vb)
{
    __shared__ __align__(16) ushort S[20480];   // 40KB; repack aliases front
    ushort* Ab0 = S;            // bf16 [128][32]
    ushort* Ab1 = S + 4096;
    ushort* Bb0 = S + 8192;
    ushort* Bb1 = S + 12288;
    ushort* Bb2 = S + 16384;
    const int id = ((blockIdx.x & 7) * 1536) + (blockIdx.x >> 3);
    const int nt = id % 6;
    const int rc0 = (id / 6) * 128;
    const int t = threadIdx.x;
    const int wid = t >> 6, l = t & 63;
    const int wm = wid >> 2, wn = wid & 3;   // 2 x 4 waves: 64m x 32n each
    const int l15 = l & 15, lhi = l >> 4;
    const int swz8 = (lhi ^ ((l15 >> 1) & 3)) * 8;
    f32x4 acc[4][2];
    #pragma unroll
    for (int a_ = 0; a_ < 4; ++a_)
        #pragma unroll
        for (int b_ = 0; b_ < 2; ++b_)
            acc[a_][b_] = (f32x4){0.f, 0.f, 0.f, 0.f};

    const float*  Ag = x + (size_t)rc0 * E_;
    const ushort* Bg = WT + (size_t)nt * 128 * E_;

    // A: thread t owns one bf16 16B chunk: row = t>>2 (0..127), slot = t&3;
    // source fp32 chunk cc = slot ^ ((row>>1)&3) (r12 key).
    const int rowA = t >> 2;
    const int ccA = (t & 3) ^ ((rowA >> 1) & 3);
    const float* Ap = Ag + (size_t)rowA * E_ + ccA * 8;
    const int wsA = rowA * 32 + (t & 3) * 8;

    float4 rA0a, rA0b;   // reg set 0 (even steps)
    float4 rA1a, rA1b;   // reg set 1 (odd steps)

#define ALOAD0(i) { rA0a = *(const float4*)(Ap + (i)*32);                        \
                    rA0b = *(const float4*)(Ap + (i)*32 + 4); }
#define ALOAD1(i) { rA1a = *(const float4*)(Ap + (i)*32);                        \
                    rA1b = *(const float4*)(Ap + (i)*32 + 4); }
#define AWRITE0(buf) { uint4 w_ = { cvtpk(rA0a.x,rA0a.y), cvtpk(rA0a.z,rA0a.w),  \
                                    cvtpk(rA0b.x,rA0b.y), cvtpk(rA0b.z,rA0b.w)}; \
                       *(uint4*)((buf) + wsA) = w_; }
#define AWRITE1(buf) { uint4 w_ = { cvtpk(rA1a.x,rA1a.y), cvtpk(rA1a.z,rA1a.w),  \
                                    cvtpk(rA1b.x,rA1b.y), cvtpk(rA1b.z,rA1b.w)}; \
                       *(uint4*)((buf) + wsA) = w_; }
#define BGLL(i, buf) { const ushort* Bi_ = Bg + (i) * 32;                        \
                       SCH(Bi_, E_, buf, t); }
#define QMFMA(As, Bs) {                                                          \
    bf16x8 af_[4], bf_[2];                                                       \
    _Pragma("unroll")                                                            \
    for (int f_ = 0; f_ < 4; ++f_)                                               \
        af_[f_] = *(const bf16x8*)((As) + (wm*64 + f_*16 + l15)*32 + swz8);      \
    _Pragma("unroll")                                                            \
    for (int g_ = 0; g_ < 2; ++g_)                                               \
        bf_[g_] = *(const bf16x8*)((Bs) + (wn*32 + g_*16 + l15)*32 + swz8);      \
    _Pragma("unroll")                                                            \
    for (int m_ = 0; m_ < 4; ++m_)                                               \
        _Pragma("unroll")                                                        \
        for (int n_ = 0; n_ < 2; ++n_)                                           \
            acc[m_][n_] = __builtin_amdgcn_mfma_f32_16x16x32_bf16(               \
                af_[m_], bf_[n_], acc[m_][n_], 0, 0, 0); }

    // Prologue: batches 0 and 1 (each = 2 A float4 loads + 1 B gll).
    ALOAD0(0); BGLL(0, Bb0);
    ALOAD1(1); BGLL(1, Bb1);

    #pragma unroll
    for (int s = 0; s < 8; ++s) {
        if (s < 7) { VMCNT(3); } else { VMCNT(0); }   // batch s landed
        SCHED0;
        if ((s & 1) == 0) { AWRITE0((s & 1) ? Ab1 : Ab0); }
        else              { AWRITE1((s & 1) ? Ab1 : Ab0); }
        LGKM0; SCHED0; ABAR; SCHED0;
        if (s + 2 < 8) {
            if ((s & 1) == 0) { ALOAD0(s + 2); }       // reuse set s&1
            else              { ALOAD1(s + 2); }
            if (((s + 2) % 3) == 0)      { BGLL(s + 2, Bb0); }
            else if (((s + 2) % 3) == 1) { BGLL(s + 2, Bb1); }
            else                         { BGLL(s + 2, Bb2); }
        }
        if ((s % 3) == 0)      { QMFMA(((s & 1) ? Ab1 : Ab0), Bb0); }
        else if ((s % 3) == 1) { QMFMA(((s & 1) ? Ab1 : Ab0), Bb1); }
        else                   { QMFMA(((s & 1) ? Ab1 : Ab0), Bb2); }
    }
    __syncthreads();   // all staging reads done before repack alias

    const int proj = nt >> 1;
    const float* bias = (proj == 0) ? bq : (proj == 1) ? bk : bv;
    float bvv[2];
    #pragma unroll
    for (int g = 0; g < 2; ++g)
        bvv[g] = bias[(nt * 128 + wn * 32 + g * 16 + l15) & 255];

    // repack: q/k as [c][e], v as [e][c]
    #pragma unroll
    for (int fm = 0; fm < 4; ++fm)
        #pragma unroll
        for (int g = 0; g < 2; ++g)
            #pragma unroll
            for (int rg = 0; rg < 4; ++rg) {
                const int m = wm * 64 + fm * 16 + lhi * 4 + rg;
                const int n = wn * 32 + g * 16 + l15;
                const ushort val = f2bf(acc[fm][g][rg] + bvv[g]);
                if (proj < 2) S[m * RP + n] = val;
                else          S[n * RP + m] = val;
            }
    __syncthreads();

    const int r = rc0 >> 9, c0 = rc0 & 511;
    if (proj < 2) {
        ushort* dst = (proj == 0) ? qb : kb;
        #pragma unroll
        for (int c = 0; c < 4; ++c) {
            const int idx = t + 512 * c;
            const int mrow = idx >> 4, ne = (idx & 15) * 8;
            uint4 w = *(const uint4*)(S + mrow * RP + ne);
            if (proj == 0) {   // q: * 1/128 * (1-mask)
                const float sk = 0.0078125f * (1.0f - mask[rc0 + mrow]);
                ushort* ws = (ushort*)&w;
                #pragma unroll
                for (int jj = 0; jj < 8; ++jj) ws[jj] = f2bf(bf2f(ws[jj]) * sk);
            }
            const int e = (nt & 1) * 128 + ne, h = e >> 5, d = e & 31;
            *(uint4*)(dst + ((((size_t)h * R_ + r) * C_) + c0 + mrow) * D_ + d) = w;
        }
    } else {
        #pragma unroll
        for (int c = 0; c < 4; ++c) {
            const int idx = t + 512 * c;
            const int nrow = idx >> 4, m0 = (idx & 15) * 8;
            uint4 w = *(const uint4*)(S + nrow * RP + m0);
            const int e = (nt & 1) * 128 + nrow, h = e >> 5, d = e & 31;
            *(uint4*)(vb + (((size_t)h * R_ + r) * D_ + d) * C_ + c0 + m0) = w;
        }
    }
#undef ALOAD0
#undef ALOAD1
#undef AWRITE0
#undef AWRITE1
#undef BGLL
#undef QMFMA
}

// ---------------------------------------------------------------------------
// Attention logits.  128x128 tile, 256 threads, K split 8-way (1024 blocks).
// partial stores non-temporal (written once, read once by softmax).
// ---------------------------------------------------------------------------
__global__ __launch_bounds__(256) void logits_mfma(
    const ushort* __restrict__ qb, const ushort* __restrict__ kb,
    float* __restrict__ partial)
{
    __shared__ __align__(16) ushort S[24576];
    BUFS3;
    const int id = ((blockIdx.x & 7) * 128) + (blockIdx.x >> 3);
    const int sub = id & 15;
    const int j0 = (sub & 3) * 128;         // j fastest: 4 blocks share q panel
    const int i0 = (sub >> 2) * 128;
    const int hks = id >> 4;                // 0..63
    const int h = hks >> 3, ks = hks & 7;
    PREAMBLE(wid >> 1, wid & 1);

    const ushort* Ab = qb + (((size_t)h * R_ + ks * 64) * C_ + i0) * D_;
    const ushort* Bb = kb + (((size_t)h * R_ + ks * 64) * C_ + j0) * D_;

#define LSTG(i, Abuf, Bbuf) {                                   \
    const ushort* Ai = Ab + (size_t)(i) * (C_ * D_);            \
    const ushort* Bi = Bb + (size_t)(i) * (C_ * D_);            \
    SCH(Ai, D_, Abuf, t); SCH(Ai, D_, Abuf, t + 256);           \
    SCH(Bi, D_, Bbuf, t); SCH(Bi, D_, Bbuf, t + 256); }
    DBUFT(LSTG, 64);

    float* dst = partial + ((size_t)ks * H_ + h) * C_ * C_;
    #pragma unroll
    for (int fm = 0; fm < 4; ++fm)
        #pragma unroll
        for (int rg = 0; rg < 4; ++rg) {
            const int i = i0 + wm * 64 + fm * 16 + lhi * 4 + rg;
            #pragma unroll
            for (int fn = 0; fn < 4; ++fn) {
                const int j = j0 + wn * 64 + fn * 16 + l15;
                __builtin_nontemporal_store(acc[fm][fn][rg],
                                            &dst[(size_t)i * C_ + j]);
            }
        }
}

// ---------------------------------------------------------------------------
// Sum 8 K-split partials (non-temporal loads: read-once) + i-axis mask +
// softmax over j.  probs stores non-temporal (terminal output); Pb cached.
// ---------------------------------------------------------------------------
__global__ __launch_bounds__(256) void softmax_kernel(
    const float* __restrict__ partial, const float* __restrict__ mask,
    float* __restrict__ probs, ushort* __restrict__ Pb)
{
    const int hi = blockIdx.x;
    const int i = hi & 511;
    const int t = threadIdx.x;
    const size_t base = (size_t)hi * C_;
    const size_t stride = (size_t)H_ * C_ * C_;
    float v0 = 0.f, v1 = 0.f;
    #pragma unroll
    for (int ksp = 0; ksp < 8; ++ksp) {
        v0 += __builtin_nontemporal_load(&partial[ksp * stride + base + t]);
        v1 += __builtin_nontemporal_load(&partial[ksp * stride + base + t + 256]);
    }
    const float mi = mask[i];
    const float keep = 1.0f - mi;
    v0 = v0 * keep + mi * (-10000.0f);
    v1 = v1 * keep + mi * (-10000.0f);

    float m = fmaxf(v0, v1);
    #pragma unroll
    for (int off = 32; off > 0; off >>= 1) m = fmaxf(m, __shfl_xor(m, off));
    __shared__ float red[4];
    if ((t & 63) == 0) red[t >> 6] = m;
    __syncthreads();
    m = fmaxf(fmaxf(red[0], red[1]), fmaxf(red[2], red[3]));

    const float e0 = expf(v0 - m), e1 = expf(v1 - m);
    float s = e0 + e1;
    #pragma unroll
    for (int off = 32; off > 0; off >>= 1) s += __shfl_xor(s, off);
    __syncthreads();
    if ((t & 63) == 0) red[t >> 6] = s;
    __syncthreads();
    s = red[0] + red[1] + red[2] + red[3];

    const float inv = 1.0f / s;
    const float p0 = e0 * inv, p1 = e1 * inv;
    __builtin_nontemporal_store(p0, &probs[base + t]);
    __builtin_nontemporal_store(p1, &probs[base + t + 256]);
    Pb[base + t] = f2bf(p0);          // Pb is small (4MB) and reused -> cached
    Pb[base + t + 256] = f2bf(p1);
}

// ---------------------------------------------------------------------------
// Context.  128x128 tile, 256 threads, 4096 blocks (one head per XCD).
// ctxb stores CACHED (re-read by out_proj; LLC can hold a large fraction).
// ---------------------------------------------------------------------------
__global__ __launch_bounds__(256) void context_mfma(
    const ushort* __restrict__ Pb, const ushort* __restrict__ vb,
    ushort* __restrict__ ctxb)
{
    __shared__ __align__(16) ushort S[24576];
    BUFS3;
    const int id = ((blockIdx.x & 7) * 512) + (blockIdx.x >> 3);
    const int i0 = (id & 3) * 128;          // i fastest: 4 blocks share vb panel
    const int n0 = ((id >> 2) & 127) * 128;
    const int h = id >> 9;
    PREAMBLE(wid >> 1, wid & 1);

    const ushort* Ab = Pb + ((size_t)h * C_ + i0) * C_;
    const ushort* Bb = vb + ((size_t)h * R_ * D_ + n0) * C_;

#define CSTG(i, Abuf, Bbuf) {                                   \
    const ushort* Ai = Ab + (i) * 32;                           \
    const ushort* Bi = Bb + (i) * 32;                           \
    SCH(Ai, C_, Abuf, t); SCH(Ai, C_, Abuf, t + 256);           \
    SCH(Bi, C_, Bbuf, t); SCH(Bi, C_, Bbuf, t + 256); }
    DBUFT(CSTG, 16);
    __syncthreads();   // staging reads done before repack alias

    #pragma unroll
    for (int fm = 0; fm < 4; ++fm)
        #pragma unroll
        for (int fn = 0; fn < 4; ++fn)
            #pragma unroll
            for (int rg = 0; rg < 4; ++rg) {
                const int m = wm * 64 + fm * 16 + lhi * 4 + rg;
                const int n = wn * 64 + fn * 16 + l15;
                S[m * RP + n] = f2bf(acc[fm][fn][rg]);
            }
    __syncthreads();

    #pragma unroll
    for (int c = 0; c < 8; ++c) {
        const int idx = t + 256 * c;
        const int mrow = idx >> 4, nl = (idx & 15) * 8;
        uint4 w = *(const uint4*)(S + mrow * RP + nl);
        const int n = n0 + nl;
        const int rr = n >> 5, d = n & 31;
        const size_t rc = (size_t)rr * C_ + i0 + mrow;
        *(uint4*)(ctxb + rc * E_ + h * D_ + d) = w;
    }
}

// ---------------------------------------------------------------------------
// Output projection.  128x128 tile, 256 threads, 4096 blocks, fp32 out.
// out stores non-temporal (terminal output, never re-read on device).
// ---------------------------------------------------------------------------
__global__ __launch_bounds__(256) void out_proj_mfma(
    const ushort* __restrict__ ctxb, const ushort* __restrict__ WoT,
    const float* __restrict__ bo, float* __restrict__ out)
{
    __shared__ __align__(16) ushort S[24576];
    BUFS3;
    float* Sf = (float*)S;                  // 128 x 68 fp32 repack (aliases)
    const int id = ((blockIdx.x & 7) * 512) + (blockIdx.x >> 3);
    const int n0 = (id & 1) * 128;
    const int rc0 = (id >> 1) * 128;
    PREAMBLE(wid >> 1, wid & 1);

    const ushort* Ab = ctxb + (size_t)rc0 * E_;
    const ushort* Bb = WoT + (size_t)n0 * E_;

#define OSTG(i, Abuf, Bbuf) {                                   \
    const ushort* Ai = Ab + (i) * 32;                           \
    const ushort* Bi = Bb + (i) * 32;                           \
    SCH(Ai, E_, Abuf, t); SCH(Ai, E_, Abuf, t + 256);           \
    SCH(Bi, E_, Bbuf, t); SCH(Bi, E_, Bbuf, t + 256); }
    DBUFT(OSTG, 8);
    __syncthreads();   // staging reads done before repack alias

    float bvv[4];
    #pragma unroll
    for (int fn = 0; fn < 4; ++fn)
        bvv[fn] = bo[n0 + wn * 64 + fn * 16 + l15];

    #pragma unroll
    for (int p = 0; p < 2; ++p) {
        #pragma unroll
        for (int fm = 0; fm < 4; ++fm)
            #pragma unroll
            for (int fh = 0; fh < 2; ++fh) {
                const int fn = 2 * p + fh;
                #pragma unroll
                for (int rg = 0; rg < 4; ++rg) {
                    const int m = wm * 64 + fm * 16 + lhi * 4 + rg;
                    const int s = wn * 32 + fh * 16 + l15;
                    Sf[m * 68 + s] = acc[fm][fn][rg] + bvv[fn];
                }
            }
        __syncthreads();
        #pragma unroll
        for (int c = 0; c < 8; ++c) {
            const int idx = t + 256 * c;
            const int row = idx >> 4, s0 = (idx & 15) * 4;
            float4 w = *(const float4*)(Sf + row * 68 + s0);
            const int ncol = n0 + (s0 >> 5) * 64 + (2 * p + ((s0 >> 4) & 1)) * 16 + (s0 & 15);
            nts_f4(out + ((size_t)rc0 + row) * E_ + ncol, w);
        }
        __syncthreads();
    }
}

// ---------------------------------------------------------------------------
extern "C" void kernel_launch(void* const* d_in, const int* in_sizes, int n_in,
                              void* d_out, int out_size, void* d_ws, size_t ws_size,
                              hipStream_t stream)
{
    const float* x    = (const float*)d_in[0];
    const float* mask = (const float*)d_in[1];
    const float* Wq   = (const float*)d_in[2];
    const float* bq   = (const float*)d_in[3];
    const float* Wk   = (const float*)d_in[4];
    const float* bk   = (const float*)d_in[5];
    const float* Wv   = (const float*)d_in[6];
    const float* bv   = (const float*)d_in[7];
    const float* Wo   = (const float*)d_in[8];
    const float* bo   = (const float*)d_in[9];

    float* out   = (float*)d_out;                       // [R,C,E] fp32
    float* probs = out + (size_t)RC_ * E_;              // [H,C,C] fp32

    char* ws = (char*)d_ws;
    ushort* qb      = (ushort*)(ws);                    // 128 MB  [h][r][c][d]
    ushort* kb      = (ushort*)(ws + 134217728ull);     // 128 MB  [h][r][c][d]
    ushort* vb      = (ushort*)(ws + 268435456ull);     // 128 MB  [h][r][d][c]
    ushort* ctxb    = (ushort*)(ws + 402653184ull);     // 128 MB  [rc][e]
    float*  partial = (float*)(ws + 536870912ull);      // 64 MB   [8][h][i][j]
    ushort* Pb      = (ushort*)(ws + 603979776ull);     // 4 MB    [h][i][j]
    ushort* WTqkv   = (ushort*)(ws + 608174080ull);     // 384 KB
    ushort* WoT     = (ushort*)(ws + 608567296ull);     // 128 KB

    convert_w<<<1024, 256, 0, stream>>>(Wq, Wk, Wv, Wo, WTqkv, WoT);
    qkv_mfma<<<12288, 512, 0, stream>>>(x, WTqkv, bq, bk, bv, mask, qb, kb, vb);
    logits_mfma<<<1024, 256, 0, stream>>>(qb, kb, partial);
    softmax_kernel<<<4096, 256, 0, stream>>>(partial, mask, probs, Pb);
    context_mfma<<<4096, 256, 0, stream>>>(Pb, vb, ctxb);
    out_proj_mfma<<<4096, 256, 0, stream>>>(ctxb, WoT, bo, out);
}

// Round 21
// 534.121 us; speedup vs baseline: 1.0964x; 1.0128x over previous
//
#include <hip/hip_runtime.h>
#include <math.h>

#define R_ 512
#define C_ 512
#define E_ 256
#define H_ 8
#define D_ 32
#define RC_ (R_*C_)   // 262144
#define RP 136        // repack pitch (ushorts)

typedef __attribute__((ext_vector_type(8))) short bf16x8;
typedef __attribute__((ext_vector_type(4))) float f32x4;
typedef __attribute__((ext_vector_type(4))) unsigned u32x4;

__device__ __forceinline__ ushort f2bf(float f) {
    union { float f; unsigned u; } v; v.f = f;
    unsigned r = v.u + 0x7FFFu + ((v.u >> 16) & 1u);   // RNE
    return (ushort)(r >> 16);
}
__device__ __forceinline__ float bf2f(ushort u) {
    union { unsigned u; float f; } v; v.u = ((unsigned)u) << 16;
    return v.f;
}
// packed f32x2 -> bf16x2 (RNE on gfx950)
__device__ __forceinline__ unsigned cvtpk(float lo, float hi) {
    unsigned r;
    asm("v_cvt_pk_bf16_f32 %0, %1, %2" : "=v"(r) : "v"(lo), "v"(hi));
    return r;
}
// Non-temporal 16B store (terminal / read-once data only).
__device__ __forceinline__ void nts_f4(float* p, float4 v) {
    f32x4 w = {v.x, v.y, v.z, v.w};
    __builtin_nontemporal_store(w, (f32x4*)p);
}

// 16B global->LDS direct copy (lane-linear dest), fallback = reg staging.
__device__ __forceinline__ void gll16(const ushort* g, ushort* l) {
#if __has_builtin(__builtin_amdgcn_global_load_lds)
    __builtin_amdgcn_global_load_lds(
        (const __attribute__((address_space(1))) unsigned*)(unsigned long long)g,
        (__attribute__((address_space(3))) unsigned*)(unsigned)(unsigned long long)l,
        16, 0, 0);
#else
    *(uint4*)l = *(const uint4*)g;
#endif
}

// Stage one 16B chunk f of a [rows][32-ushort] bf16 tile.  Source slot
// XOR-swizzled with (row>>1)&3 (r12-proven key).  LDS dest lane-linear.
#define SCH(gbase, stride, lds, f)                                               \
    gll16((gbase) + (size_t)((f) >> 2) * (stride)                                \
              + (((((f) & 3) ^ ((((f) >> 2) >> 1) & 3))) << 3),                  \
          (lds) + (f) * 8)

// --- Fenced sync primitives (validated r11/r12: rule #18 double-fence).
#define SCHED0   __builtin_amdgcn_sched_barrier(0)
#define ABAR     __builtin_amdgcn_s_barrier()
#define VMCNT(N) asm volatile("s_waitcnt vmcnt(" #N ")" ::: "memory")
#define LGKM0    asm volatile("s_waitcnt lgkmcnt(0)" ::: "memory")

// Per-wave 64x64 output, 16x16x32 bf16 MFMA, K=32 per step, 32-ushort rows.
#define PREAMBLE(WM, WN)                                \
    const int t = threadIdx.x;                          \
    const int wid = t >> 6, l = t & 63;                 \
    const int wm = (WM), wn = (WN);                     \
    const int l15 = l & 15, lhi = l >> 4;               \
    const int swz8 = (lhi ^ ((l15 >> 1) & 3)) * 8;      \
    f32x4 acc[4][4];                                    \
    _Pragma("unroll")                                   \
    for (int a_ = 0; a_ < 4; ++a_)                      \
        _Pragma("unroll")                               \
        for (int b_ = 0; b_ < 4; ++b_)                  \
            acc[a_][b_] = (f32x4){0.f, 0.f, 0.f, 0.f};

#define MFMA_STEP(As, Bs)                                                        \
    {                                                                            \
        bf16x8 af_[4], bf_[4];                                                   \
        _Pragma("unroll")                                                        \
        for (int f_ = 0; f_ < 4; ++f_) {                                         \
            af_[f_] = *(const bf16x8*)((As) + (wm*64 + f_*16 + l15)*32 + swz8);  \
            bf_[f_] = *(const bf16x8*)((Bs) + (wn*64 + f_*16 + l15)*32 + swz8);  \
        }                                                                        \
        _Pragma("unroll")                                                        \
        for (int m_ = 0; m_ < 4; ++m_)                                           \
            _Pragma("unroll")                                                    \
            for (int n_ = 0; n_ < 4; ++n_)                                       \
                acc[m_][n_] = __builtin_amdgcn_mfma_f32_16x16x32_bf16(           \
                    af_[m_], bf_[n_], acc[m_][n_], 0, 0, 0);                     \
    }

// Triple-buffered K-loop, ONE fenced barrier per step, prefetch distance 2
// (validated r12).  Requires A0..A2/B0..B2; each STG = 4 gll16/thread.
#define DBUFT(STG, NIT)                                                          \
    STG(0, A0, B0); STG(1, A1, B1);                                              \
    _Pragma("unroll")                                                            \
    for (int s = 0; s < (NIT); ++s) {                                            \
        if (s < (NIT) - 1) { VMCNT(4); } else { VMCNT(0); }                      \
        SCHED0; ABAR; SCHED0;                                                    \
        if (s + 2 < (NIT)) {                                                     \
            if (((s + 2) % 3) == 0)      { STG(s + 2, A0, B0); }                 \
            else if (((s + 2) % 3) == 1) { STG(s + 2, A1, B1); }                 \
            else                         { STG(s + 2, A2, B2); }                 \
        }                                                                        \
        if ((s % 3) == 0)      { MFMA_STEP(A0, B0); }                            \
        else if ((s % 3) == 1) { MFMA_STEP(A1, B1); }                            \
        else                   { MFMA_STEP(A2, B2); }                            \
    }

#define BUFS3 ushort* A0 = S;          ushort* B0 = S + 4096;                    \
              ushort* A1 = S + 8192;   ushort* B1 = S + 12288;                   \
              ushort* A2 = S + 16384;  ushort* B2 = S + 20480;

// ---------------------------------------------------------------------------
// Weights -> n-major bf16.  Wq is pre-scaled by 1/128 (exact pow2: folding
// the align_scaling into the weights removes the q epilogue's second
// rounding pass; mask-zeroing remains a pure select since mask is binary).
// ---------------------------------------------------------------------------
__global__ __launch_bounds__(256) void convert_w(
    const float* __restrict__ Wq, const float* __restrict__ Wk,
    const float* __restrict__ Wv, const float* __restrict__ Wo,
    ushort* __restrict__ WTqkv, ushort* __restrict__ WoT)
{
    const int id = blockIdx.x;      // 0..1023
    const int matn = id >> 8;
    const int n = id & 255;
    const int k = threadIdx.x;
    const float* W = (matn == 0) ? Wq : (matn == 1) ? Wk : (matn == 2) ? Wv : Wo;
    float wv = W[(size_t)k * E_ + n];
    if (matn == 0) wv *= 0.0078125f;   // fold D^-0.5/sqrt(R) = 1/128 into Wq
    ushort v = f2bf(wv);
    if (matn < 3) WTqkv[((size_t)matn * E_ + n) * E_ + k] = v;
    else          WoT[(size_t)n * E_ + k] = v;
}

// ---------------------------------------------------------------------------
// Fused QKV projection: 512 threads (8 waves 2x4), 128x128 tile.  Fenced
// reg-staged schedule (r16/r20, measured best): 2 A float4 + 1 B gll per
// thread, VMCNT(3); LDS 40KB.  Epilogue stores CACHED (re-read downstream).
// q scaling is pre-folded into Wq/bq; mask zeroing is a vector select.
// ---------------------------------------------------------------------------
__global__ __launch_bounds__(512) void qkv_mfma(
    const float* __restrict__ x, const ushort* __restrict__ WT,
    const float* __restrict__ bq, const float* __restrict__ bk,
    const float* __restrict__ bv, const float* __restrict__ mask,
    ushort* __restrict__ qb, ushort* __restrict__ kb, ushort* __restrict__ vb)
{
    __shared__ __align__(16) ushort S[20480];   // 40KB; repack aliases front
    ushort* Ab0 = S;            // bf16 [128][32]
    ushort* Ab1 = S + 4096;
    ushort* Bb0 = S + 8192;
    ushort* Bb1 = S + 12288;
    ushort* Bb2 = S + 16384;
    const int id = ((blockIdx.x & 7) * 1536) + (blockIdx.x >> 3);
    const int nt = id % 6;
    const int rc0 = (id / 6) * 128;
    const int t = threadIdx.x;
    const int wid = t >> 6, l = t & 63;
    const int wm = wid >> 2, wn = wid & 3;   // 2 x 4 waves: 64m x 32n each
    const int l15 = l & 15, lhi = l >> 4;
    const int swz8 = (lhi ^ ((l15 >> 1) & 3)) * 8;
    f32x4 acc[4][2];
    #pragma unroll
    for (int a_ = 0; a_ < 4; ++a_)
        #pragma unroll
        for (int b_ = 0; b_ < 2; ++b_)
            acc[a_][b_] = (f32x4){0.f, 0.f, 0.f, 0.f};

    const float*  Ag = x + (size_t)rc0 * E_;
    const ushort* Bg = WT + (size_t)nt * 128 * E_;

    // A: thread t owns one bf16 16B chunk: row = t>>2 (0..127), slot = t&3;
    // source fp32 chunk cc = slot ^ ((row>>1)&3) (r12 key).
    const int rowA = t >> 2;
    const int ccA = (t & 3) ^ ((rowA >> 1) & 3);
    const float* Ap = Ag + (size_t)rowA * E_ + ccA * 8;
    const int wsA = rowA * 32 + (t & 3) * 8;

    float4 rA0a, rA0b;   // reg set 0 (even steps)
    float4 rA1a, rA1b;   // reg set 1 (odd steps)

#define ALOAD0(i) { rA0a = *(const float4*)(Ap + (i)*32);                        \
                    rA0b = *(const float4*)(Ap + (i)*32 + 4); }
#define ALOAD1(i) { rA1a = *(const float4*)(Ap + (i)*32);                        \
                    rA1b = *(const float4*)(Ap + (i)*32 + 4); }
#define AWRITE0(buf) { uint4 w_ = { cvtpk(rA0a.x,rA0a.y), cvtpk(rA0a.z,rA0a.w),  \
                                    cvtpk(rA0b.x,rA0b.y), cvtpk(rA0b.z,rA0b.w)}; \
                       *(uint4*)((buf) + wsA) = w_; }
#define AWRITE1(buf) { uint4 w_ = { cvtpk(rA1a.x,rA1a.y), cvtpk(rA1a.z,rA1a.w),  \
                                    cvtpk(rA1b.x,rA1b.y), cvtpk(rA1b.z,rA1b.w)}; \
                       *(uint4*)((buf) + wsA) = w_; }
#define BGLL(i, buf) { const ushort* Bi_ = Bg + (i) * 32;                        \
                       SCH(Bi_, E_, buf, t); }
#define QMFMA(As, Bs) {                                                          \
    bf16x8 af_[4], bf_[2];                                                       \
    _Pragma("unroll")                                                            \
    for (int f_ = 0; f_ < 4; ++f_)                                               \
        af_[f_] = *(const bf16x8*)((As) + (wm*64 + f_*16 + l15)*32 + swz8);      \
    _Pragma("unroll")                                                            \
    for (int g_ = 0; g_ < 2; ++g_)                                               \
        bf_[g_] = *(const bf16x8*)((Bs) + (wn*32 + g_*16 + l15)*32 + swz8);      \
    _Pragma("unroll")                                                            \
    for (int m_ = 0; m_ < 4; ++m_)                                               \
        _Pragma("unroll")                                                        \
        for (int n_ = 0; n_ < 2; ++n_)                                           \
            acc[m_][n_] = __builtin_amdgcn_mfma_f32_16x16x32_bf16(               \
                af_[m_], bf_[n_], acc[m_][n_], 0, 0, 0); }

    // Prologue: batches 0 and 1 (each = 2 A float4 loads + 1 B gll).
    ALOAD0(0); BGLL(0, Bb0);
    ALOAD1(1); BGLL(1, Bb1);

    #pragma unroll
    for (int s = 0; s < 8; ++s) {
        if (s < 7) { VMCNT(3); } else { VMCNT(0); }   // batch s landed
        SCHED0;
        if ((s & 1) == 0) { AWRITE0((s & 1) ? Ab1 : Ab0); }
        else              { AWRITE1((s & 1) ? Ab1 : Ab0); }
        LGKM0; SCHED0; ABAR; SCHED0;
        if (s + 2 < 8) {
            if ((s & 1) == 0) { ALOAD0(s + 2); }       // reuse set s&1
            else              { ALOAD1(s + 2); }
            if (((s + 2) % 3) == 0)      { BGLL(s + 2, Bb0); }
            else if (((s + 2) % 3) == 1) { BGLL(s + 2, Bb1); }
            else                         { BGLL(s + 2, Bb2); }
        }
        if ((s % 3) == 0)      { QMFMA(((s & 1) ? Ab1 : Ab0), Bb0); }
        else if ((s % 3) == 1) { QMFMA(((s & 1) ? Ab1 : Ab0), Bb1); }
        else                   { QMFMA(((s & 1) ? Ab1 : Ab0), Bb2); }
    }
    __syncthreads();   // all staging reads done before repack alias

    const int proj = nt >> 1;
    const float* bias = (proj == 0) ? bq : (proj == 1) ? bk : bv;
    const float bsc = (proj == 0) ? 0.0078125f : 1.0f;   // fold scale into bq
    float bvv[2];
    #pragma unroll
    for (int g = 0; g < 2; ++g)
        bvv[g] = bias[(nt * 128 + wn * 32 + g * 16 + l15) & 255] * bsc;

    // repack: q/k as [c][e], v as [e][c]
    #pragma unroll
    for (int fm = 0; fm < 4; ++fm)
        #pragma unroll
        for (int g = 0; g < 2; ++g)
            #pragma unroll
            for (int rg = 0; rg < 4; ++rg) {
                const int m = wm * 64 + fm * 16 + lhi * 4 + rg;
                const int n = wn * 32 + g * 16 + l15;
                const ushort val = f2bf(acc[fm][g][rg] + bvv[g]);
                if (proj < 2) S[m * RP + n] = val;
                else          S[n * RP + m] = val;
            }
    __syncthreads();

    const int r = rc0 >> 9, c0 = rc0 & 511;
    if (proj < 2) {
        ushort* dst = (proj == 0) ? qb : kb;
        #pragma unroll
        for (int c = 0; c < 4; ++c) {
            const int idx = t + 512 * c;
            const int mrow = idx >> 4, ne = (idx & 15) * 8;
            uint4 w = *(const uint4*)(S + mrow * RP + ne);
            if (proj == 0 && mask[rc0 + mrow] != 0.0f)   // binary mask: zero row
                w = make_uint4(0u, 0u, 0u, 0u);
            const int e = (nt & 1) * 128 + ne, h = e >> 5, d = e & 31;
            *(uint4*)(dst + ((((size_t)h * R_ + r) * C_) + c0 + mrow) * D_ + d) = w;
        }
    } else {
        #pragma unroll
        for (int c = 0; c < 4; ++c) {
            const int idx = t + 512 * c;
            const int nrow = idx >> 4, m0 = (idx & 15) * 8;
            uint4 w = *(const uint4*)(S + nrow * RP + m0);
            const int e = (nt & 1) * 128 + nrow, h = e >> 5, d = e & 31;
            *(uint4*)(vb + (((size_t)h * R_ + r) * D_ + d) * C_ + c0 + m0) = w;
        }
    }
#undef ALOAD0
#undef ALOAD1
#undef AWRITE0
#undef AWRITE1
#undef BGLL
#undef QMFMA
}

// ---------------------------------------------------------------------------
// Attention logits.  128x128 tile, 256 threads, K split 8-way (1024 blocks).
// partial stores non-temporal (written once, read once by softmax).
// ---------------------------------------------------------------------------
__global__ __launch_bounds__(256) void logits_mfma(
    const ushort* __restrict__ qb, const ushort* __restrict__ kb,
    float* __restrict__ partial)
{
    __shared__ __align__(16) ushort S[24576];
    BUFS3;
    const int id = ((blockIdx.x & 7) * 128) + (blockIdx.x >> 3);
    const int sub = id & 15;
    const int j0 = (sub & 3) * 128;         // j fastest: 4 blocks share q panel
    const int i0 = (sub >> 2) * 128;
    const int hks = id >> 4;                // 0..63
    const int h = hks >> 3, ks = hks & 7;
    PREAMBLE(wid >> 1, wid & 1);

    const ushort* Ab = qb + (((size_t)h * R_ + ks * 64) * C_ + i0) * D_;
    const ushort* Bb = kb + (((size_t)h * R_ + ks * 64) * C_ + j0) * D_;

#define LSTG(i, Abuf, Bbuf) {                                   \
    const ushort* Ai = Ab + (size_t)(i) * (C_ * D_);            \
    const ushort* Bi = Bb + (size_t)(i) * (C_ * D_);            \
    SCH(Ai, D_, Abuf, t); SCH(Ai, D_, Abuf, t + 256);           \
    SCH(Bi, D_, Bbuf, t); SCH(Bi, D_, Bbuf, t + 256); }
    DBUFT(LSTG, 64);

    float* dst = partial + ((size_t)ks * H_ + h) * C_ * C_;
    #pragma unroll
    for (int fm = 0; fm < 4; ++fm)
        #pragma unroll
        for (int rg = 0; rg < 4; ++rg) {
            const int i = i0 + wm * 64 + fm * 16 + lhi * 4 + rg;
            #pragma unroll
            for (int fn = 0; fn < 4; ++fn) {
                const int j = j0 + wn * 64 + fn * 16 + l15;
                __builtin_nontemporal_store(acc[fm][fn][rg],
                                            &dst[(size_t)i * C_ + j]);
            }
        }
}

// ---------------------------------------------------------------------------
// Sum 8 K-split partials (non-temporal loads: read-once) + i-axis mask +
// softmax over j.  probs stores non-temporal (terminal output); Pb cached.
// ---------------------------------------------------------------------------
__global__ __launch_bounds__(256) void softmax_kernel(
    const float* __restrict__ partial, const float* __restrict__ mask,
    float* __restrict__ probs, ushort* __restrict__ Pb)
{
    const int hi = blockIdx.x;
    const int i = hi & 511;
    const int t = threadIdx.x;
    const size_t base = (size_t)hi * C_;
    const size_t stride = (size_t)H_ * C_ * C_;
    float v0 = 0.f, v1 = 0.f;
    #pragma unroll
    for (int ksp = 0; ksp < 8; ++ksp) {
        v0 += __builtin_nontemporal_load(&partial[ksp * stride + base + t]);
        v1 += __builtin_nontemporal_load(&partial[ksp * stride + base + t + 256]);
    }
    const float mi = mask[i];
    const float keep = 1.0f - mi;
    v0 = v0 * keep + mi * (-10000.0f);
    v1 = v1 * keep + mi * (-10000.0f);

    float m = fmaxf(v0, v1);
    #pragma unroll
    for (int off = 32; off > 0; off >>= 1) m = fmaxf(m, __shfl_xor(m, off));
    __shared__ float red[4];
    if ((t & 63) == 0) red[t >> 6] = m;
    __syncthreads();
    m = fmaxf(fmaxf(red[0], red[1]), fmaxf(red[2], red[3]));

    const float e0 = expf(v0 - m), e1 = expf(v1 - m);
    float s = e0 + e1;
    #pragma unroll
    for (int off = 32; off > 0; off >>= 1) s += __shfl_xor(s, off);
    __syncthreads();
    if ((t & 63) == 0) red[t >> 6] = s;
    __syncthreads();
    s = red[0] + red[1] + red[2] + red[3];

    const float inv = 1.0f / s;
    const float p0 = e0 * inv, p1 = e1 * inv;
    __builtin_nontemporal_store(p0, &probs[base + t]);
    __builtin_nontemporal_store(p1, &probs[base + t + 256]);
    Pb[base + t] = f2bf(p0);          // Pb is small (4MB) and reused -> cached
    Pb[base + t + 256] = f2bf(p1);
}

// ---------------------------------------------------------------------------
// Context.  128x128 tile, 256 threads, 4096 blocks (one head per XCD).
// ctxb stores CACHED (re-read by out_proj).
// ---------------------------------------------------------------------------
__global__ __launch_bounds__(256) void context_mfma(
    const ushort* __restrict__ Pb, const ushort* __restrict__ vb,
    ushort* __restrict__ ctxb)
{
    __shared__ __align__(16) ushort S[24576];
    BUFS3;
    const int id = ((blockIdx.x & 7) * 512) + (blockIdx.x >> 3);
    const int i0 = (id & 3) * 128;          // i fastest: 4 blocks share vb panel
    const int n0 = ((id >> 2) & 127) * 128;
    const int h = id >> 9;
    PREAMBLE(wid >> 1, wid & 1);

    const ushort* Ab = Pb + ((size_t)h * C_ + i0) * C_;
    const ushort* Bb = vb + ((size_t)h * R_ * D_ + n0) * C_;

#define CSTG(i, Abuf, Bbuf) {                                   \
    const ushort* Ai = Ab + (i) * 32;                           \
    const ushort* Bi = Bb + (i) * 32;                           \
    SCH(Ai, C_, Abuf, t); SCH(Ai, C_, Abuf, t + 256);           \
    SCH(Bi, C_, Bbuf, t); SCH(Bi, C_, Bbuf, t + 256); }
    DBUFT(CSTG, 16);
    __syncthreads();   // staging reads done before repack alias

    #pragma unroll
    for (int fm = 0; fm < 4; ++fm)
        #pragma unroll
        for (int fn = 0; fn < 4; ++fn)
            #pragma unroll
            for (int rg = 0; rg < 4; ++rg) {
                const int m = wm * 64 + fm * 16 + lhi * 4 + rg;
                const int n = wn * 64 + fn * 16 + l15;
                S[m * RP + n] = f2bf(acc[fm][fn][rg]);
            }
    __syncthreads();

    #pragma unroll
    for (int c = 0; c < 8; ++c) {
        const int idx = t + 256 * c;
        const int mrow = idx >> 4, nl = (idx & 15) * 8;
        uint4 w = *(const uint4*)(S + mrow * RP + nl);
        const int n = n0 + nl;
        const int rr = n >> 5, d = n & 31;
        const size_t rc = (size_t)rr * C_ + i0 + mrow;
        *(uint4*)(ctxb + rc * E_ + h * D_ + d) = w;
    }
}

// ---------------------------------------------------------------------------
// Output projection.  128x128 tile, 256 threads, 4096 blocks, fp32 out.
// out stores non-temporal (terminal output, never re-read on device).
// ---------------------------------------------------------------------------
__global__ __launch_bounds__(256) void out_proj_mfma(
    const ushort* __restrict__ ctxb, const ushort* __restrict__ WoT,
    const float* __restrict__ bo, float* __restrict__ out)
{
    __shared__ __align__(16) ushort S[24576];
    BUFS3;
    float* Sf = (float*)S;                  // 128 x 68 fp32 repack (aliases)
    const int id = ((blockIdx.x & 7) * 512) + (blockIdx.x >> 3);
    const int n0 = (id & 1) * 128;
    const int rc0 = (id >> 1) * 128;
    PREAMBLE(wid >> 1, wid & 1);

    const ushort* Ab = ctxb + (size_t)rc0 * E_;
    const ushort* Bb = WoT + (size_t)n0 * E_;

#define OSTG(i, Abuf, Bbuf) {                                   \
    const ushort* Ai = Ab + (i) * 32;                           \
    const ushort* Bi = Bb + (i) * 32;                           \
    SCH(Ai, E_, Abuf, t); SCH(Ai, E_, Abuf, t + 256);           \
    SCH(Bi, E_, Bbuf, t); SCH(Bi, E_, Bbuf, t + 256); }
    DBUFT(OSTG, 8);
    __syncthreads();   // staging reads done before repack alias

    float bvv[4];
    #pragma unroll
    for (int fn = 0; fn < 4; ++fn)
        bvv[fn] = bo[n0 + wn * 64 + fn * 16 + l15];

    #pragma unroll
    for (int p = 0; p < 2; ++p) {
        #pragma unroll
        for (int fm = 0; fm < 4; ++fm)
            #pragma unroll
            for (int fh = 0; fh < 2; ++fh) {
                const int fn = 2 * p + fh;
                #pragma unroll
                for (int rg = 0; rg < 4; ++rg) {
                    const int m = wm * 64 + fm * 16 + lhi * 4 + rg;
                    const int s = wn * 32 + fh * 16 + l15;
                    Sf[m * 68 + s] = acc[fm][fn][rg] + bvv[fn];
                }
            }
        __syncthreads();
        #pragma unroll
        for (int c = 0; c < 8; ++c) {
            const int idx = t + 256 * c;
            const int row = idx >> 4, s0 = (idx & 15) * 4;
            float4 w = *(const float4*)(Sf + row * 68 + s0);
            const int ncol = n0 + (s0 >> 5) * 64 + (2 * p + ((s0 >> 4) & 1)) * 16 + (s0 & 15);
            nts_f4(out + ((size_t)rc0 + row) * E_ + ncol, w);
        }
        __syncthreads();
    }
}

// ---------------------------------------------------------------------------
extern "C" void kernel_launch(void* const* d_in, const int* in_sizes, int n_in,
                              void* d_out, int out_size, void* d_ws, size_t ws_size,
                              hipStream_t stream)
{
    const float* x    = (const float*)d_in[0];
    const float* mask = (const float*)d_in[1];
    const float* Wq   = (const float*)d_in[2];
    const float* bq   = (const float*)d_in[3];
    const float* Wk   = (const float*)d_in[4];
    const float* bk   = (const float*)d_in[5];
    const float* Wv   = (const float*)d_in[6];
    const float* bv   = (const float*)d_in[7];
    const float* Wo   = (const float*)d_in[8];
    const float* bo   = (const float*)d_in[9];

    float* out   = (float*)d_out;                       // [R,C,E] fp32
    float* probs = out + (size_t)RC_ * E_;              // [H,C,C] fp32

    char* ws = (char*)d_ws;
    ushort* qb      = (ushort*)(ws);                    // 128 MB  [h][r][c][d]
    ushort* kb      = (ushort*)(ws + 134217728ull);     // 128 MB  [h][r][c][d]
    ushort* vb      = (ushort*)(ws + 268435456ull);     // 128 MB  [h][r][d][c]
    ushort* ctxb    = (ushort*)(ws + 402653184ull);     // 128 MB  [rc][e]
    float*  partial = (float*)(ws + 536870912ull);      // 64 MB   [8][h][i][j]
    ushort* Pb      = (ushort*)(ws + 603979776ull);     // 4 MB    [h][i][j]
    ushort* WTqkv   = (ushort*)(ws + 608174080ull);     // 384 KB
    ushort* WoT     = (ushort*)(ws + 608567296ull);     // 128 KB

    convert_w<<<1024, 256, 0, stream>>>(Wq, Wk, Wv, Wo, WTqkv, WoT);
    qkv_mfma<<<12288, 512, 0, stream>>>(x, WTqkv, bq, bk, bv, mask, qb, kb, vb);
    logits_mfma<<<1024, 256, 0, stream>>>(qb, kb, partial);
    softmax_kernel<<<4096, 256, 0, stream>>>(partial, mask, probs, Pb);
    context_mfma<<<4096, 256, 0, stream>>>(Pb, vb, ctxb);
    out_proj_mfma<<<4096, 256, 0, stream>>>(ctxb, WoT, bo, out);
}

// Round 22
// 530.066 us; speedup vs baseline: 1.1048x; 1.0077x over previous
//
#include <hip/hip_runtime.h>
#include <math.h>

#define R_ 512
#define C_ 512
#define E_ 256
#define H_ 8
#define D_ 32
#define RC_ (R_*C_)   // 262144
#define RP 136        // repack pitch (ushorts)

typedef __attribute__((ext_vector_type(8))) short bf16x8;
typedef __attribute__((ext_vector_type(4))) float f32x4;
typedef __attribute__((ext_vector_type(4))) unsigned u32x4;

__device__ __forceinline__ ushort f2bf(float f) {
    union { float f; unsigned u; } v; v.f = f;
    unsigned r = v.u + 0x7FFFu + ((v.u >> 16) & 1u);   // RNE
    return (ushort)(r >> 16);
}
__device__ __forceinline__ float bf2f(ushort u) {
    union { unsigned u; float f; } v; v.u = ((unsigned)u) << 16;
    return v.f;
}
// packed f32x2 -> bf16x2 (RNE on gfx950)
__device__ __forceinline__ unsigned cvtpk(float lo, float hi) {
    unsigned r;
    asm("v_cvt_pk_bf16_f32 %0, %1, %2" : "=v"(r) : "v"(lo), "v"(hi));
    return r;
}
// Non-temporal 16B store (terminal / read-once data only).
__device__ __forceinline__ void nts_f4(float* p, float4 v) {
    f32x4 w = {v.x, v.y, v.z, v.w};
    __builtin_nontemporal_store(w, (f32x4*)p);
}

// 16B global->LDS direct copy (lane-linear dest), fallback = reg staging.
__device__ __forceinline__ void gll16(const ushort* g, ushort* l) {
#if __has_builtin(__builtin_amdgcn_global_load_lds)
    __builtin_amdgcn_global_load_lds(
        (const __attribute__((address_space(1))) unsigned*)(unsigned long long)g,
        (__attribute__((address_space(3))) unsigned*)(unsigned)(unsigned long long)l,
        16, 0, 0);
#else
    *(uint4*)l = *(const uint4*)g;
#endif
}

// Stage one 16B chunk f of a [rows][32-ushort] bf16 tile.  Source slot
// XOR-swizzled with (row>>1)&3 (r12-proven key).  LDS dest lane-linear.
#define SCH(gbase, stride, lds, f)                                               \
    gll16((gbase) + (size_t)((f) >> 2) * (stride)                                \
              + (((((f) & 3) ^ ((((f) >> 2) >> 1) & 3))) << 3),                  \
          (lds) + (f) * 8)

// --- Fenced sync primitives (validated r11/r12: rule #18 double-fence).
#define SCHED0   __builtin_amdgcn_sched_barrier(0)
#define ABAR     __builtin_amdgcn_s_barrier()
#define VMCNT(N) asm volatile("s_waitcnt vmcnt(" #N ")" ::: "memory")
#define LGKM0    asm volatile("s_waitcnt lgkmcnt(0)" ::: "memory")

// Per-wave 64x64 output, 16x16x32 bf16 MFMA, K=32 per step, 32-ushort rows.
#define PREAMBLE(WM, WN)                                \
    const int t = threadIdx.x;                          \
    const int wid = t >> 6, l = t & 63;                 \
    const int wm = (WM), wn = (WN);                     \
    const int l15 = l & 15, lhi = l >> 4;               \
    const int swz8 = (lhi ^ ((l15 >> 1) & 3)) * 8;      \
    f32x4 acc[4][4];                                    \
    _Pragma("unroll")                                   \
    for (int a_ = 0; a_ < 4; ++a_)                      \
        _Pragma("unroll")                               \
        for (int b_ = 0; b_ < 4; ++b_)                  \
            acc[a_][b_] = (f32x4){0.f, 0.f, 0.f, 0.f};

#define MFMA_STEP(As, Bs)                                                        \
    {                                                                            \
        bf16x8 af_[4], bf_[4];                                                   \
        _Pragma("unroll")                                                        \
        for (int f_ = 0; f_ < 4; ++f_) {                                         \
            af_[f_] = *(const bf16x8*)((As) + (wm*64 + f_*16 + l15)*32 + swz8);  \
            bf_[f_] = *(const bf16x8*)((Bs) + (wn*64 + f_*16 + l15)*32 + swz8);  \
        }                                                                        \
        _Pragma("unroll")                                                        \
        for (int m_ = 0; m_ < 4; ++m_)                                           \
            _Pragma("unroll")                                                    \
            for (int n_ = 0; n_ < 4; ++n_)                                       \
                acc[m_][n_] = __builtin_amdgcn_mfma_f32_16x16x32_bf16(           \
                    af_[m_], bf_[n_], acc[m_][n_], 0, 0, 0);                     \
    }

// Triple-buffered K-loop, ONE fenced barrier per step, prefetch distance 2
// (validated r12).  Requires A0..A2/B0..B2; each STG = 4 gll16/thread.
#define DBUFT(STG, NIT)                                                          \
    STG(0, A0, B0); STG(1, A1, B1);                                              \
    _Pragma("unroll")                                                            \
    for (int s = 0; s < (NIT); ++s) {                                            \
        if (s < (NIT) - 1) { VMCNT(4); } else { VMCNT(0); }                      \
        SCHED0; ABAR; SCHED0;                                                    \
        if (s + 2 < (NIT)) {                                                     \
            if (((s + 2) % 3) == 0)      { STG(s + 2, A0, B0); }                 \
            else if (((s + 2) % 3) == 1) { STG(s + 2, A1, B1); }                 \
            else                         { STG(s + 2, A2, B2); }                 \
        }                                                                        \
        if ((s % 3) == 0)      { MFMA_STEP(A0, B0); }                            \
        else if ((s % 3) == 1) { MFMA_STEP(A1, B1); }                            \
        else                   { MFMA_STEP(A2, B2); }                            \
    }

#define BUFS3 ushort* A0 = S;          ushort* B0 = S + 4096;                    \
              ushort* A1 = S + 8192;   ushort* B1 = S + 12288;                   \
              ushort* A2 = S + 16384;  ushort* B2 = S + 20480;

// ---------------------------------------------------------------------------
// Weights -> n-major bf16.  Wq pre-scaled by 1/128 (exact pow2).
// ---------------------------------------------------------------------------
__global__ __launch_bounds__(256) void convert_w(
    const float* __restrict__ Wq, const float* __restrict__ Wk,
    const float* __restrict__ Wv, const float* __restrict__ Wo,
    ushort* __restrict__ WTqkv, ushort* __restrict__ WoT)
{
    const int id = blockIdx.x;      // 0..1023
    const int matn = id >> 8;
    const int n = id & 255;
    const int k = threadIdx.x;
    const float* W = (matn == 0) ? Wq : (matn == 1) ? Wk : (matn == 2) ? Wv : Wo;
    float wv = W[(size_t)k * E_ + n];
    if (matn == 0) wv *= 0.0078125f;   // fold D^-0.5/sqrt(R) = 1/128 into Wq
    ushort v = f2bf(wv);
    if (matn < 3) WTqkv[((size_t)matn * E_ + n) * E_ + k] = v;
    else          WoT[(size_t)n * E_ + k] = v;
}

// ---------------------------------------------------------------------------
// Fused QKV projection: 512 threads (8 waves 2x4), 128x128 tile.  Fenced
// reg-staged schedule (r16/r20 best): 2 A float4 + 1 B gll per thread,
// VMCNT(3); LDS 40KB.  Cached epilogue stores; scale folded into Wq/bq;
// binary mask -> zero-row select.
// ---------------------------------------------------------------------------
__global__ __launch_bounds__(512) void qkv_mfma(
    const float* __restrict__ x, const ushort* __restrict__ WT,
    const float* __restrict__ bq, const float* __restrict__ bk,
    const float* __restrict__ bv, const float* __restrict__ mask,
    ushort* __restrict__ qb, ushort* __restrict__ kb, ushort* __restrict__ vb)
{
    __shared__ __align__(16) ushort S[20480];   // 40KB; repack aliases front
    ushort* Ab0 = S;            // bf16 [128][32]
    ushort* Ab1 = S + 4096;
    ushort* Bb0 = S + 8192;
    ushort* Bb1 = S + 12288;
    ushort* Bb2 = S + 16384;
    const int id = ((blockIdx.x & 7) * 1536) + (blockIdx.x >> 3);
    const int nt = id % 6;
    const int rc0 = (id / 6) * 128;
    const int t = threadIdx.x;
    const int wid = t >> 6, l = t & 63;
    const int wm = wid >> 2, wn = wid & 3;   // 2 x 4 waves: 64m x 32n each
    const int l15 = l & 15, lhi = l >> 4;
    const int swz8 = (lhi ^ ((l15 >> 1) & 3)) * 8;
    f32x4 acc[4][2];
    #pragma unroll
    for (int a_ = 0; a_ < 4; ++a_)
        #pragma unroll
        for (int b_ = 0; b_ < 2; ++b_)
            acc[a_][b_] = (f32x4){0.f, 0.f, 0.f, 0.f};

    const float*  Ag = x + (size_t)rc0 * E_;
    const ushort* Bg = WT + (size_t)nt * 128 * E_;

    const int rowA = t >> 2;
    const int ccA = (t & 3) ^ ((rowA >> 1) & 3);
    const float* Ap = Ag + (size_t)rowA * E_ + ccA * 8;
    const int wsA = rowA * 32 + (t & 3) * 8;

    float4 rA0a, rA0b;   // reg set 0 (even steps)
    float4 rA1a, rA1b;   // reg set 1 (odd steps)

#define ALOAD0(i) { rA0a = *(const float4*)(Ap + (i)*32);                        \
                    rA0b = *(const float4*)(Ap + (i)*32 + 4); }
#define ALOAD1(i) { rA1a = *(const float4*)(Ap + (i)*32);                        \
                    rA1b = *(const float4*)(Ap + (i)*32 + 4); }
#define AWRITE0(buf) { uint4 w_ = { cvtpk(rA0a.x,rA0a.y), cvtpk(rA0a.z,rA0a.w),  \
                                    cvtpk(rA0b.x,rA0b.y), cvtpk(rA0b.z,rA0b.w)}; \
                       *(uint4*)((buf) + wsA) = w_; }
#define AWRITE1(buf) { uint4 w_ = { cvtpk(rA1a.x,rA1a.y), cvtpk(rA1a.z,rA1a.w),  \
                                    cvtpk(rA1b.x,rA1b.y), cvtpk(rA1b.z,rA1b.w)}; \
                       *(uint4*)((buf) + wsA) = w_; }
#define BGLL(i, buf) { const ushort* Bi_ = Bg + (i) * 32;                        \
                       SCH(Bi_, E_, buf, t); }
#define QMFMA(As, Bs) {                                                          \
    bf16x8 af_[4], bf_[2];                                                       \
    _Pragma("unroll")                                                            \
    for (int f_ = 0; f_ < 4; ++f_)                                               \
        af_[f_] = *(const bf16x8*)((As) + (wm*64 + f_*16 + l15)*32 + swz8);      \
    _Pragma("unroll")                                                            \
    for (int g_ = 0; g_ < 2; ++g_)                                               \
        bf_[g_] = *(const bf16x8*)((Bs) + (wn*32 + g_*16 + l15)*32 + swz8);      \
    _Pragma("unroll")                                                            \
    for (int m_ = 0; m_ < 4; ++m_)                                               \
        _Pragma("unroll")                                                        \
        for (int n_ = 0; n_ < 2; ++n_)                                           \
            acc[m_][n_] = __builtin_amdgcn_mfma_f32_16x16x32_bf16(               \
                af_[m_], bf_[n_], acc[m_][n_], 0, 0, 0); }

    // Prologue: batches 0 and 1 (each = 2 A float4 loads + 1 B gll).
    ALOAD0(0); BGLL(0, Bb0);
    ALOAD1(1); BGLL(1, Bb1);

    #pragma unroll
    for (int s = 0; s < 8; ++s) {
        if (s < 7) { VMCNT(3); } else { VMCNT(0); }   // batch s landed
        SCHED0;
        if ((s & 1) == 0) { AWRITE0((s & 1) ? Ab1 : Ab0); }
        else              { AWRITE1((s & 1) ? Ab1 : Ab0); }
        LGKM0; SCHED0; ABAR; SCHED0;
        if (s + 2 < 8) {
            if ((s & 1) == 0) { ALOAD0(s + 2); }       // reuse set s&1
            else              { ALOAD1(s + 2); }
            if (((s + 2) % 3) == 0)      { BGLL(s + 2, Bb0); }
            else if (((s + 2) % 3) == 1) { BGLL(s + 2, Bb1); }
            else                         { BGLL(s + 2, Bb2); }
        }
        if ((s % 3) == 0)      { QMFMA(((s & 1) ? Ab1 : Ab0), Bb0); }
        else if ((s % 3) == 1) { QMFMA(((s & 1) ? Ab1 : Ab0), Bb1); }
        else                   { QMFMA(((s & 1) ? Ab1 : Ab0), Bb2); }
    }
    __syncthreads();   // all staging reads done before repack alias

    const int proj = nt >> 1;
    const float* bias = (proj == 0) ? bq : (proj == 1) ? bk : bv;
    const float bsc = (proj == 0) ? 0.0078125f : 1.0f;   // fold scale into bq
    float bvv[2];
    #pragma unroll
    for (int g = 0; g < 2; ++g)
        bvv[g] = bias[(nt * 128 + wn * 32 + g * 16 + l15) & 255] * bsc;

    // repack: q/k as [c][e], v as [e][c]
    #pragma unroll
    for (int fm = 0; fm < 4; ++fm)
        #pragma unroll
        for (int g = 0; g < 2; ++g)
            #pragma unroll
            for (int rg = 0; rg < 4; ++rg) {
                const int m = wm * 64 + fm * 16 + lhi * 4 + rg;
                const int n = wn * 32 + g * 16 + l15;
                const ushort val = f2bf(acc[fm][g][rg] + bvv[g]);
                if (proj < 2) S[m * RP + n] = val;
                else          S[n * RP + m] = val;
            }
    __syncthreads();

    const int r = rc0 >> 9, c0 = rc0 & 511;
    if (proj < 2) {
        ushort* dst = (proj == 0) ? qb : kb;
        #pragma unroll
        for (int c = 0; c < 4; ++c) {
            const int idx = t + 512 * c;
            const int mrow = idx >> 4, ne = (idx & 15) * 8;
            uint4 w = *(const uint4*)(S + mrow * RP + ne);
            if (proj == 0 && mask[rc0 + mrow] != 0.0f)   // binary mask: zero row
                w = make_uint4(0u, 0u, 0u, 0u);
            const int e = (nt & 1) * 128 + ne, h = e >> 5, d = e & 31;
            *(uint4*)(dst + ((((size_t)h * R_ + r) * C_) + c0 + mrow) * D_ + d) = w;
        }
    } else {
        #pragma unroll
        for (int c = 0; c < 4; ++c) {
            const int idx = t + 512 * c;
            const int nrow = idx >> 4, m0 = (idx & 15) * 8;
            uint4 w = *(const uint4*)(S + nrow * RP + m0);
            const int e = (nt & 1) * 128 + nrow, h = e >> 5, d = e & 31;
            *(uint4*)(vb + (((size_t)h * R_ + r) * D_ + d) * C_ + c0 + m0) = w;
        }
    }
#undef ALOAD0
#undef ALOAD1
#undef AWRITE0
#undef AWRITE1
#undef BGLL
#undef QMFMA
}

// ---------------------------------------------------------------------------
// Attention logits.  128x128 tile, 256 threads, K split 4-WAY (512 blocks).
// ROLLED 3-step-group K-loop (126 = 3*42 main + 2-step tail): same per-step
// fenced sync as validated DBUFT but ~1.5KB body (the 64-step full unroll
// was at the 32KB L1I limit; 128 steps must be rolled).  partial stores NT.
// ---------------------------------------------------------------------------
__global__ __launch_bounds__(256) void logits_mfma(
    const ushort* __restrict__ qb, const ushort* __restrict__ kb,
    float* __restrict__ partial)
{
    __shared__ __align__(16) ushort S[24576];
    BUFS3;
    const int id = ((blockIdx.x & 7) * 64) + (blockIdx.x >> 3);   // 0..511
    const int sub = id & 15;
    const int j0 = (sub & 3) * 128;         // j fastest: 4 blocks share q panel
    const int i0 = (sub >> 2) * 128;
    const int hks = id >> 4;                // 0..31
    const int h = hks >> 2, ks = hks & 3;
    PREAMBLE(wid >> 1, wid & 1);

    const ushort* Ab = qb + (((size_t)h * R_ + ks * 128) * C_ + i0) * D_;
    const ushort* Bb = kb + (((size_t)h * R_ + ks * 128) * C_ + j0) * D_;

#define LSTG(i, Abuf, Bbuf) {                                   \
    const ushort* Ai = Ab + (size_t)(i) * (C_ * D_);            \
    const ushort* Bi = Bb + (size_t)(i) * (C_ * D_);            \
    SCH(Ai, D_, Abuf, t); SCH(Ai, D_, Abuf, t + 256);           \
    SCH(Bi, D_, Bbuf, t); SCH(Bi, D_, Bbuf, t + 256); }

    // Prologue + rolled main loop (steps 0..125 in 42 groups of 3) + tail.
    LSTG(0, A0, B0); LSTG(1, A1, B1);
    for (int q = 0; q < 42; ++q) {
        const int s = 3 * q;
        VMCNT(4); SCHED0; ABAR; SCHED0; LSTG(s + 2, A2, B2); MFMA_STEP(A0, B0);
        VMCNT(4); SCHED0; ABAR; SCHED0; LSTG(s + 3, A0, B0); MFMA_STEP(A1, B1);
        VMCNT(4); SCHED0; ABAR; SCHED0; LSTG(s + 4, A1, B1); MFMA_STEP(A2, B2);
    }
    // s=126 (buf 0, staged at s=124): one batch (127's) still in flight.
    VMCNT(4); SCHED0; ABAR; SCHED0; MFMA_STEP(A0, B0);
    // s=127 (buf 1, staged at s=125): final drain.
    VMCNT(0); SCHED0; ABAR; SCHED0; MFMA_STEP(A1, B1);

    float* dst = partial + ((size_t)ks * H_ + h) * C_ * C_;
    #pragma unroll
    for (int fm = 0; fm < 4; ++fm)
        #pragma unroll
        for (int rg = 0; rg < 4; ++rg) {
            const int i = i0 + wm * 64 + fm * 16 + lhi * 4 + rg;
            #pragma unroll
            for (int fn = 0; fn < 4; ++fn) {
                const int j = j0 + wn * 64 + fn * 16 + l15;
                __builtin_nontemporal_store(acc[fm][fn][rg],
                                            &dst[(size_t)i * C_ + j]);
            }
        }
}

// ---------------------------------------------------------------------------
// Sum 4 K-split partials (non-temporal loads: read-once) + i-axis mask +
// softmax over j.  probs stores non-temporal (terminal); Pb cached.
// ---------------------------------------------------------------------------
__global__ __launch_bounds__(256) void softmax_kernel(
    const float* __restrict__ partial, const float* __restrict__ mask,
    float* __restrict__ probs, ushort* __restrict__ Pb)
{
    const int hi = blockIdx.x;
    const int i = hi & 511;
    const int t = threadIdx.x;
    const size_t base = (size_t)hi * C_;
    const size_t stride = (size_t)H_ * C_ * C_;
    float v0 = 0.f, v1 = 0.f;
    #pragma unroll
    for (int ksp = 0; ksp < 4; ++ksp) {
        v0 += __builtin_nontemporal_load(&partial[ksp * stride + base + t]);
        v1 += __builtin_nontemporal_load(&partial[ksp * stride + base + t + 256]);
    }
    const float mi = mask[i];
    const float keep = 1.0f - mi;
    v0 = v0 * keep + mi * (-10000.0f);
    v1 = v1 * keep + mi * (-10000.0f);

    float m = fmaxf(v0, v1);
    #pragma unroll
    for (int off = 32; off > 0; off >>= 1) m = fmaxf(m, __shfl_xor(m, off));
    __shared__ float red[4];
    if ((t & 63) == 0) red[t >> 6] = m;
    __syncthreads();
    m = fmaxf(fmaxf(red[0], red[1]), fmaxf(red[2], red[3]));

    const float e0 = expf(v0 - m), e1 = expf(v1 - m);
    float s = e0 + e1;
    #pragma unroll
    for (int off = 32; off > 0; off >>= 1) s += __shfl_xor(s, off);
    __syncthreads();
    if ((t & 63) == 0) red[t >> 6] = s;
    __syncthreads();
    s = red[0] + red[1] + red[2] + red[3];

    const float inv = 1.0f / s;
    const float p0 = e0 * inv, p1 = e1 * inv;
    __builtin_nontemporal_store(p0, &probs[base + t]);
    __builtin_nontemporal_store(p1, &probs[base + t + 256]);
    Pb[base + t] = f2bf(p0);          // Pb small (4MB) and reused -> cached
    Pb[base + t + 256] = f2bf(p1);
}

// ---------------------------------------------------------------------------
// Context.  128x128 tile, 256 threads, 4096 blocks (one head per XCD).
// ctxb stores CACHED (re-read by out_proj).
// ---------------------------------------------------------------------------
__global__ __launch_bounds__(256) void context_mfma(
    const ushort* __restrict__ Pb, const ushort* __restrict__ vb,
    ushort* __restrict__ ctxb)
{
    __shared__ __align__(16) ushort S[24576];
    BUFS3;
    const int id = ((blockIdx.x & 7) * 512) + (blockIdx.x >> 3);
    const int i0 = (id & 3) * 128;          // i fastest: 4 blocks share vb panel
    const int n0 = ((id >> 2) & 127) * 128;
    const int h = id >> 9;
    PREAMBLE(wid >> 1, wid & 1);

    const ushort* Ab = Pb + ((size_t)h * C_ + i0) * C_;
    const ushort* Bb = vb + ((size_t)h * R_ * D_ + n0) * C_;

#define CSTG(i, Abuf, Bbuf) {                                   \
    const ushort* Ai = Ab + (i) * 32;                           \
    const ushort* Bi = Bb + (i) * 32;                           \
    SCH(Ai, C_, Abuf, t); SCH(Ai, C_, Abuf, t + 256);           \
    SCH(Bi, C_, Bbuf, t); SCH(Bi, C_, Bbuf, t + 256); }
    DBUFT(CSTG, 16);
    __syncthreads();   // staging reads done before repack alias

    #pragma unroll
    for (int fm = 0; fm < 4; ++fm)
        #pragma unroll
        for (int fn = 0; fn < 4; ++fn)
            #pragma unroll
            for (int rg = 0; rg < 4; ++rg) {
                const int m = wm * 64 + fm * 16 + lhi * 4 + rg;
                const int n = wn * 64 + fn * 16 + l15;
                S[m * RP + n] = f2bf(acc[fm][fn][rg]);
            }
    __syncthreads();

    #pragma unroll
    for (int c = 0; c < 8; ++c) {
        const int idx = t + 256 * c;
        const int mrow = idx >> 4, nl = (idx & 15) * 8;
        uint4 w = *(const uint4*)(S + mrow * RP + nl);
        const int n = n0 + nl;
        const int rr = n >> 5, d = n & 31;
        const size_t rc = (size_t)rr * C_ + i0 + mrow;
        *(uint4*)(ctxb + rc * E_ + h * D_ + d) = w;
    }
}

// ---------------------------------------------------------------------------
// Output projection.  128x128 tile, 256 threads, 4096 blocks, fp32 out.
// out stores non-temporal (terminal output, never re-read on device).
// ---------------------------------------------------------------------------
__global__ __launch_bounds__(256) void out_proj_mfma(
    const ushort* __restrict__ ctxb, const ushort* __restrict__ WoT,
    const float* __restrict__ bo, float* __restrict__ out)
{
    __shared__ __align__(16) ushort S[24576];
    BUFS3;
    float* Sf = (float*)S;                  // 128 x 68 fp32 repack (aliases)
    const int id = ((blockIdx.x & 7) * 512) + (blockIdx.x >> 3);
    const int n0 = (id & 1) * 128;
    const int rc0 = (id >> 1) * 128;
    PREAMBLE(wid >> 1, wid & 1);

    const ushort* Ab = ctxb + (size_t)rc0 * E_;
    const ushort* Bb = WoT + (size_t)n0 * E_;

#define OSTG(i, Abuf, Bbuf) {                                   \
    const ushort* Ai = Ab + (i) * 32;                           \
    const ushort* Bi = Bb + (i) * 32;                           \
    SCH(Ai, E_, Abuf, t); SCH(Ai, E_, Abuf, t + 256);           \
    SCH(Bi, E_, Bbuf, t); SCH(Bi, E_, Bbuf, t + 256); }
    DBUFT(OSTG, 8);
    __syncthreads();   // staging reads done before repack alias

    float bvv[4];
    #pragma unroll
    for (int fn = 0; fn < 4; ++fn)
        bvv[fn] = bo[n0 + wn * 64 + fn * 16 + l15];

    #pragma unroll
    for (int p = 0; p < 2; ++p) {
        #pragma unroll
        for (int fm = 0; fm < 4; ++fm)
            #pragma unroll
            for (int fh = 0; fh < 2; ++fh) {
                const int fn = 2 * p + fh;
                #pragma unroll
                for (int rg = 0; rg < 4; ++rg) {
                    const int m = wm * 64 + fm * 16 + lhi * 4 + rg;
                    const int s = wn * 32 + fh * 16 + l15;
                    Sf[m * 68 + s] = acc[fm][fn][rg] + bvv[fn];
                }
            }
        __syncthreads();
        #pragma unroll
        for (int c = 0; c < 8; ++c) {
            const int idx = t + 256 * c;
            const int row = idx >> 4, s0 = (idx & 15) * 4;
            float4 w = *(const float4*)(Sf + row * 68 + s0);
            const int ncol = n0 + (s0 >> 5) * 64 + (2 * p + ((s0 >> 4) & 1)) * 16 + (s0 & 15);
            nts_f4(out + ((size_t)rc0 + row) * E_ + ncol, w);
        }
        __syncthreads();
    }
}

// ---------------------------------------------------------------------------
extern "C" void kernel_launch(void* const* d_in, const int* in_sizes, int n_in,
                              void* d_out, int out_size, void* d_ws, size_t ws_size,
                              hipStream_t stream)
{
    const float* x    = (const float*)d_in[0];
    const float* mask = (const float*)d_in[1];
    const float* Wq   = (const float*)d_in[2];
    const float* bq   = (const float*)d_in[3];
    const float* Wk   = (const float*)d_in[4];
    const float* bk   = (const float*)d_in[5];
    const float* Wv   = (const float*)d_in[6];
    const float* bv   = (const float*)d_in[7];
    const float* Wo   = (const float*)d_in[8];
    const float* bo   = (const float*)d_in[9];

    float* out   = (float*)d_out;                       // [R,C,E] fp32
    float* probs = out + (size_t)RC_ * E_;              // [H,C,C] fp32

    char* ws = (char*)d_ws;
    ushort* qb      = (ushort*)(ws);                    // 128 MB  [h][r][c][d]
    ushort* kb      = (ushort*)(ws + 134217728ull);     // 128 MB  [h][r][c][d]
    ushort* vb      = (ushort*)(ws + 268435456ull);     // 128 MB  [h][r][d][c]
    ushort* ctxb    = (ushort*)(ws + 402653184ull);     // 128 MB  [rc][e]
    float*  partial = (float*)(ws + 536870912ull);      // 32 MB   [4][h][i][j]
    ushort* Pb      = (ushort*)(ws + 603979776ull);     // 4 MB    [h][i][j]
    ushort* WTqkv   = (ushort*)(ws + 608174080ull);     // 384 KB
    ushort* WoT     = (ushort*)(ws + 608567296ull);     // 128 KB

    convert_w<<<1024, 256, 0, stream>>>(Wq, Wk, Wv, Wo, WTqkv, WoT);
    qkv_mfma<<<12288, 512, 0, stream>>>(x, WTqkv, bq, bk, bv, mask, qb, kb, vb);
    logits_mfma<<<512, 256, 0, stream>>>(qb, kb, partial);
    softmax_kernel<<<4096, 256, 0, stream>>>(partial, mask, probs, Pb);
    context_mfma<<<4096, 256, 0, stream>>>(Pb, vb, ctxb);
    out_proj_mfma<<<4096, 256, 0, stream>>>(ctxb, WoT, bo, out);
}

// Round 23
// 528.945 us; speedup vs baseline: 1.1071x; 1.0021x over previous
//
#include <hip/hip_runtime.h>
#include <math.h>

#define R_ 512
#define C_ 512
#define E_ 256
#define H_ 8
#define D_ 32
#define RC_ (R_*C_)   // 262144
#define RP 136        // repack pitch (ushorts)

typedef __attribute__((ext_vector_type(8))) short bf16x8;
typedef __attribute__((ext_vector_type(4))) float f32x4;
typedef __attribute__((ext_vector_type(4))) unsigned u32x4;

__device__ __forceinline__ ushort f2bf(float f) {
    union { float f; unsigned u; } v; v.f = f;
    unsigned r = v.u + 0x7FFFu + ((v.u >> 16) & 1u);   // RNE
    return (ushort)(r >> 16);
}
__device__ __forceinline__ float bf2f(ushort u) {
    union { unsigned u; float f; } v; v.u = ((unsigned)u) << 16;
    return v.f;
}
// packed f32x2 -> bf16x2 (RNE on gfx950)
__device__ __forceinline__ unsigned cvtpk(float lo, float hi) {
    unsigned r;
    asm("v_cvt_pk_bf16_f32 %0, %1, %2" : "=v"(r) : "v"(lo), "v"(hi));
    return r;
}
// Non-temporal 16B store (terminal / read-once data only).
__device__ __forceinline__ void nts_f4(float* p, float4 v) {
    f32x4 w = {v.x, v.y, v.z, v.w};
    __builtin_nontemporal_store(w, (f32x4*)p);
}

// 16B global->LDS direct copy (lane-linear dest), fallback = reg staging.
__device__ __forceinline__ void gll16(const ushort* g, ushort* l) {
#if __has_builtin(__builtin_amdgcn_global_load_lds)
    __builtin_amdgcn_global_load_lds(
        (const __attribute__((address_space(1))) unsigned*)(unsigned long long)g,
        (__attribute__((address_space(3))) unsigned*)(unsigned)(unsigned long long)l,
        16, 0, 0);
#else
    *(uint4*)l = *(const uint4*)g;
#endif
}

// Stage one 16B chunk f of a [rows][32-ushort] bf16 tile.  Source slot
// XOR-swizzled with (row>>1)&3 (r12-proven key).  LDS dest lane-linear.
#define SCH(gbase, stride, lds, f)                                               \
    gll16((gbase) + (size_t)((f) >> 2) * (stride)                                \
              + (((((f) & 3) ^ ((((f) >> 2) >> 1) & 3))) << 3),                  \
          (lds) + (f) * 8)

// --- Fenced sync primitives (validated r11/r12: rule #18 double-fence).
#define SCHED0   __builtin_amdgcn_sched_barrier(0)
#define ABAR     __builtin_amdgcn_s_barrier()
#define VMCNT(N) asm volatile("s_waitcnt vmcnt(" #N ")" ::: "memory")
#define LGKM0    asm volatile("s_waitcnt lgkmcnt(0)" ::: "memory")

// Per-wave 64x64 output, 16x16x32 bf16 MFMA, K=32 per step, 32-ushort rows.
#define PREAMBLE(WM, WN)                                \
    const int t = threadIdx.x;                          \
    const int wid = t >> 6, l = t & 63;                 \
    const int wm = (WM), wn = (WN);                     \
    const int l15 = l & 15, lhi = l >> 4;               \
    const int swz8 = (lhi ^ ((l15 >> 1) & 3)) * 8;      \
    f32x4 acc[4][4];                                    \
    _Pragma("unroll")                                   \
    for (int a_ = 0; a_ < 4; ++a_)                      \
        _Pragma("unroll")                               \
        for (int b_ = 0; b_ < 4; ++b_)                  \
            acc[a_][b_] = (f32x4){0.f, 0.f, 0.f, 0.f};

#define MFMA_STEP(As, Bs)                                                        \
    {                                                                            \
        bf16x8 af_[4], bf_[4];                                                   \
        _Pragma("unroll")                                                        \
        for (int f_ = 0; f_ < 4; ++f_) {                                         \
            af_[f_] = *(const bf16x8*)((As) + (wm*64 + f_*16 + l15)*32 + swz8);  \
            bf_[f_] = *(const bf16x8*)((Bs) + (wn*64 + f_*16 + l15)*32 + swz8);  \
        }                                                                        \
        _Pragma("unroll")                                                        \
        for (int m_ = 0; m_ < 4; ++m_)                                           \
            _Pragma("unroll")                                                    \
            for (int n_ = 0; n_ < 4; ++n_)                                       \
                acc[m_][n_] = __builtin_amdgcn_mfma_f32_16x16x32_bf16(           \
                    af_[m_], bf_[n_], acc[m_][n_], 0, 0, 0);                     \
    }

// Triple-buffered K-loop, ONE fenced barrier per step, prefetch distance 2
// (validated r12).  Requires A0..A2/B0..B2; each STG = 4 gll16/thread.
#define DBUFT(STG, NIT)                                                          \
    STG(0, A0, B0); STG(1, A1, B1);                                              \
    _Pragma("unroll")                                                            \
    for (int s = 0; s < (NIT); ++s) {                                            \
        if (s < (NIT) - 1) { VMCNT(4); } else { VMCNT(0); }                      \
        SCHED0; ABAR; SCHED0;                                                    \
        if (s + 2 < (NIT)) {                                                     \
            if (((s + 2) % 3) == 0)      { STG(s + 2, A0, B0); }                 \
            else if (((s + 2) % 3) == 1) { STG(s + 2, A1, B1); }                 \
            else                         { STG(s + 2, A2, B2); }                 \
        }                                                                        \
        if ((s % 3) == 0)      { MFMA_STEP(A0, B0); }                            \
        else if ((s % 3) == 1) { MFMA_STEP(A1, B1); }                            \
        else                   { MFMA_STEP(A2, B2); }                            \
    }

#define BUFS3 ushort* A0 = S;          ushort* B0 = S + 4096;                    \
              ushort* A1 = S + 8192;   ushort* B1 = S + 12288;                   \
              ushort* A2 = S + 16384;  ushort* B2 = S + 20480;

// ---------------------------------------------------------------------------
// Weights -> n-major bf16.  Wq pre-scaled by 1/128 (exact pow2).
// ---------------------------------------------------------------------------
__global__ __launch_bounds__(256) void convert_w(
    const float* __restrict__ Wq, const float* __restrict__ Wk,
    const float* __restrict__ Wv, const float* __restrict__ Wo,
    ushort* __restrict__ WTqkv, ushort* __restrict__ WoT)
{
    const int id = blockIdx.x;      // 0..1023
    const int matn = id >> 8;
    const int n = id & 255;
    const int k = threadIdx.x;
    const float* W = (matn == 0) ? Wq : (matn == 1) ? Wk : (matn == 2) ? Wv : Wo;
    float wv = W[(size_t)k * E_ + n];
    if (matn == 0) wv *= 0.0078125f;   // fold D^-0.5/sqrt(R) = 1/128 into Wq
    ushort v = f2bf(wv);
    if (matn < 3) WTqkv[((size_t)matn * E_ + n) * E_ + k] = v;
    else          WoT[(size_t)n * E_ + k] = v;
}

// ---------------------------------------------------------------------------
// Fused QKV projection: 512 threads (8 waves 2x4), 128x128 tile.  A-prefetch
// DEPTH 3 (3 reg sets; x misses L2 at ~900cy, 2 steps were too short), B
// depth 2 (L2-resident).  Issue order per step: BGLL(s+2) then ALOAD(s+3);
// in-order vmcnt => VMCNT(5) guarantees batch s (B gll + A loads) landed
// while A(s+1),B(s+1),A(s+2) stay in flight.  LDS unchanged 40KB.
// ---------------------------------------------------------------------------
__global__ __launch_bounds__(512) void qkv_mfma(
    const float* __restrict__ x, const ushort* __restrict__ WT,
    const float* __restrict__ bq, const float* __restrict__ bk,
    const float* __restrict__ bv, const float* __restrict__ mask,
    ushort* __restrict__ qb, ushort* __restrict__ kb, ushort* __restrict__ vb)
{
    __shared__ __align__(16) ushort S[20480];   // 40KB; repack aliases front
    ushort* Ab0 = S;            // bf16 [128][32]
    ushort* Ab1 = S + 4096;
    ushort* Bb0 = S + 8192;
    ushort* Bb1 = S + 12288;
    ushort* Bb2 = S + 16384;
    const int id = ((blockIdx.x & 7) * 1536) + (blockIdx.x >> 3);
    const int nt = id % 6;
    const int rc0 = (id / 6) * 128;
    const int t = threadIdx.x;
    const int wid = t >> 6, l = t & 63;
    const int wm = wid >> 2, wn = wid & 3;   // 2 x 4 waves: 64m x 32n each
    const int l15 = l & 15, lhi = l >> 4;
    const int swz8 = (lhi ^ ((l15 >> 1) & 3)) * 8;
    f32x4 acc[4][2];
    #pragma unroll
    for (int a_ = 0; a_ < 4; ++a_)
        #pragma unroll
        for (int b_ = 0; b_ < 2; ++b_)
            acc[a_][b_] = (f32x4){0.f, 0.f, 0.f, 0.f};

    const float*  Ag = x + (size_t)rc0 * E_;
    const ushort* Bg = WT + (size_t)nt * 128 * E_;

    const int rowA = t >> 2;
    const int ccA = (t & 3) ^ ((rowA >> 1) & 3);
    const float* Ap = Ag + (size_t)rowA * E_ + ccA * 8;
    const int wsA = rowA * 32 + (t & 3) * 8;

    float4 rA0a, rA0b;   // reg set 0 (steps 0,3,6)
    float4 rA1a, rA1b;   // reg set 1 (steps 1,4,7)
    float4 rA2a, rA2b;   // reg set 2 (steps 2,5)

#define ALOAD0(i) { rA0a = *(const float4*)(Ap + (i)*32);                        \
                    rA0b = *(const float4*)(Ap + (i)*32 + 4); }
#define ALOAD1(i) { rA1a = *(const float4*)(Ap + (i)*32);                        \
                    rA1b = *(const float4*)(Ap + (i)*32 + 4); }
#define ALOAD2(i) { rA2a = *(const float4*)(Ap + (i)*32);                        \
                    rA2b = *(const float4*)(Ap + (i)*32 + 4); }
#define AWRITE0(buf) { uint4 w_ = { cvtpk(rA0a.x,rA0a.y), cvtpk(rA0a.z,rA0a.w),  \
                                    cvtpk(rA0b.x,rA0b.y), cvtpk(rA0b.z,rA0b.w)}; \
                       *(uint4*)((buf) + wsA) = w_; }
#define AWRITE1(buf) { uint4 w_ = { cvtpk(rA1a.x,rA1a.y), cvtpk(rA1a.z,rA1a.w),  \
                                    cvtpk(rA1b.x,rA1b.y), cvtpk(rA1b.z,rA1b.w)}; \
                       *(uint4*)((buf) + wsA) = w_; }
#define AWRITE2(buf) { uint4 w_ = { cvtpk(rA2a.x,rA2a.y), cvtpk(rA2a.z,rA2a.w),  \
                                    cvtpk(rA2b.x,rA2b.y), cvtpk(rA2b.z,rA2b.w)}; \
                       *(uint4*)((buf) + wsA) = w_; }
#define BGLL(i, buf) { const ushort* Bi_ = Bg + (i) * 32;                        \
                       SCH(Bi_, E_, buf, t); }
#define QMFMA(As, Bs) {                                                          \
    bf16x8 af_[4], bf_[2];                                                       \
    _Pragma("unroll")                                                            \
    for (int f_ = 0; f_ < 4; ++f_)                                               \
        af_[f_] = *(const bf16x8*)((As) + (wm*64 + f_*16 + l15)*32 + swz8);      \
    _Pragma("unroll")                                                            \
    for (int g_ = 0; g_ < 2; ++g_)                                               \
        bf_[g_] = *(const bf16x8*)((Bs) + (wn*32 + g_*16 + l15)*32 + swz8);      \
    _Pragma("unroll")                                                            \
    for (int m_ = 0; m_ < 4; ++m_)                                               \
        _Pragma("unroll")                                                        \
        for (int n_ = 0; n_ < 2; ++n_)                                           \
            acc[m_][n_] = __builtin_amdgcn_mfma_f32_16x16x32_bf16(               \
                af_[m_], bf_[n_], acc[m_][n_], 0, 0, 0); }

    // Prologue (issue order defines vmcnt counting):
    // ALOAD(0), BGLL(0), ALOAD(1), BGLL(1), ALOAD(2).
    ALOAD0(0); BGLL(0, Bb0);
    ALOAD1(1); BGLL(1, Bb1);
    ALOAD2(2);

    #pragma unroll
    for (int s = 0; s < 8; ++s) {
        // Wait batch s landed: newer ops in flight = A(s+1),B(s+1),A(s+2) = 5.
        if (s < 6)      { VMCNT(5); }
        else if (s == 6){ VMCNT(3); }
        else            { VMCNT(0); }
        SCHED0;
        if ((s % 3) == 0)      { AWRITE0((s & 1) ? Ab1 : Ab0); }
        else if ((s % 3) == 1) { AWRITE1((s & 1) ? Ab1 : Ab0); }
        else                   { AWRITE2((s & 1) ? Ab1 : Ab0); }
        LGKM0; SCHED0; ABAR; SCHED0;
        if (s + 2 < 8) {       // B depth 2: buf (s+2)%3, readers done (s-1)
            if (((s + 2) % 3) == 0)      { BGLL(s + 2, Bb0); }
            else if (((s + 2) % 3) == 1) { BGLL(s + 2, Bb1); }
            else                         { BGLL(s + 2, Bb2); }
        }
        if (s + 3 < 8) {       // A depth 3 into the set just consumed
            if ((s % 3) == 0)      { ALOAD0(s + 3); }
            else if ((s % 3) == 1) { ALOAD1(s + 3); }
            else                   { ALOAD2(s + 3); }
        }
        if ((s % 3) == 0)      { QMFMA(((s & 1) ? Ab1 : Ab0), Bb0); }
        else if ((s % 3) == 1) { QMFMA(((s & 1) ? Ab1 : Ab0), Bb1); }
        else                   { QMFMA(((s & 1) ? Ab1 : Ab0), Bb2); }
    }
    __syncthreads();   // all staging reads done before repack alias

    const int proj = nt >> 1;
    const float* bias = (proj == 0) ? bq : (proj == 1) ? bk : bv;
    const float bsc = (proj == 0) ? 0.0078125f : 1.0f;   // fold scale into bq
    float bvv[2];
    #pragma unroll
    for (int g = 0; g < 2; ++g)
        bvv[g] = bias[(nt * 128 + wn * 32 + g * 16 + l15) & 255] * bsc;

    // repack: q/k as [c][e], v as [e][c]
    #pragma unroll
    for (int fm = 0; fm < 4; ++fm)
        #pragma unroll
        for (int g = 0; g < 2; ++g)
            #pragma unroll
            for (int rg = 0; rg < 4; ++rg) {
                const int m = wm * 64 + fm * 16 + lhi * 4 + rg;
                const int n = wn * 32 + g * 16 + l15;
                const ushort val = f2bf(acc[fm][g][rg] + bvv[g]);
                if (proj < 2) S[m * RP + n] = val;
                else          S[n * RP + m] = val;
            }
    __syncthreads();

    const int r = rc0 >> 9, c0 = rc0 & 511;
    if (proj < 2) {
        ushort* dst = (proj == 0) ? qb : kb;
        #pragma unroll
        for (int c = 0; c < 4; ++c) {
            const int idx = t + 512 * c;
            const int mrow = idx >> 4, ne = (idx & 15) * 8;
            uint4 w = *(const uint4*)(S + mrow * RP + ne);
            if (proj == 0 && mask[rc0 + mrow] != 0.0f)   // binary mask: zero row
                w = make_uint4(0u, 0u, 0u, 0u);
            const int e = (nt & 1) * 128 + ne, h = e >> 5, d = e & 31;
            *(uint4*)(dst + ((((size_t)h * R_ + r) * C_) + c0 + mrow) * D_ + d) = w;
        }
    } else {
        #pragma unroll
        for (int c = 0; c < 4; ++c) {
            const int idx = t + 512 * c;
            const int nrow = idx >> 4, m0 = (idx & 15) * 8;
            uint4 w = *(const uint4*)(S + nrow * RP + m0);
            const int e = (nt & 1) * 128 + nrow, h = e >> 5, d = e & 31;
            *(uint4*)(vb + (((size_t)h * R_ + r) * D_ + d) * C_ + c0 + m0) = w;
        }
    }
#undef ALOAD0
#undef ALOAD1
#undef ALOAD2
#undef AWRITE0
#undef AWRITE1
#undef AWRITE2
#undef BGLL
#undef QMFMA
}

// ---------------------------------------------------------------------------
// Attention logits.  128x128 tile, 256 threads, K split 4-way (512 blocks).
// Rolled 3-step-group K-loop (validated r22).  partial stores NT.
// ---------------------------------------------------------------------------
__global__ __launch_bounds__(256) void logits_mfma(
    const ushort* __restrict__ qb, const ushort* __restrict__ kb,
    float* __restrict__ partial)
{
    __shared__ __align__(16) ushort S[24576];
    BUFS3;
    const int id = ((blockIdx.x & 7) * 64) + (blockIdx.x >> 3);   // 0..511
    const int sub = id & 15;
    const int j0 = (sub & 3) * 128;         // j fastest: 4 blocks share q panel
    const int i0 = (sub >> 2) * 128;
    const int hks = id >> 4;                // 0..31
    const int h = hks >> 2, ks = hks & 3;
    PREAMBLE(wid >> 1, wid & 1);

    const ushort* Ab = qb + (((size_t)h * R_ + ks * 128) * C_ + i0) * D_;
    const ushort* Bb = kb + (((size_t)h * R_ + ks * 128) * C_ + j0) * D_;

#define LSTG(i, Abuf, Bbuf) {                                   \
    const ushort* Ai = Ab + (size_t)(i) * (C_ * D_);            \
    const ushort* Bi = Bb + (size_t)(i) * (C_ * D_);            \
    SCH(Ai, D_, Abuf, t); SCH(Ai, D_, Abuf, t + 256);           \
    SCH(Bi, D_, Bbuf, t); SCH(Bi, D_, Bbuf, t + 256); }

    LSTG(0, A0, B0); LSTG(1, A1, B1);
    for (int q = 0; q < 42; ++q) {
        const int s = 3 * q;
        VMCNT(4); SCHED0; ABAR; SCHED0; LSTG(s + 2, A2, B2); MFMA_STEP(A0, B0);
        VMCNT(4); SCHED0; ABAR; SCHED0; LSTG(s + 3, A0, B0); MFMA_STEP(A1, B1);
        VMCNT(4); SCHED0; ABAR; SCHED0; LSTG(s + 4, A1, B1); MFMA_STEP(A2, B2);
    }
    VMCNT(4); SCHED0; ABAR; SCHED0; MFMA_STEP(A0, B0);
    VMCNT(0); SCHED0; ABAR; SCHED0; MFMA_STEP(A1, B1);

    float* dst = partial + ((size_t)ks * H_ + h) * C_ * C_;
    #pragma unroll
    for (int fm = 0; fm < 4; ++fm)
        #pragma unroll
        for (int rg = 0; rg < 4; ++rg) {
            const int i = i0 + wm * 64 + fm * 16 + lhi * 4 + rg;
            #pragma unroll
            for (int fn = 0; fn < 4; ++fn) {
                const int j = j0 + wn * 64 + fn * 16 + l15;
                __builtin_nontemporal_store(acc[fm][fn][rg],
                                            &dst[(size_t)i * C_ + j]);
            }
        }
}

// ---------------------------------------------------------------------------
// Sum 4 K-split partials (NT loads) + i-axis mask + softmax over j.
// ---------------------------------------------------------------------------
__global__ __launch_bounds__(256) void softmax_kernel(
    const float* __restrict__ partial, const float* __restrict__ mask,
    float* __restrict__ probs, ushort* __restrict__ Pb)
{
    const int hi = blockIdx.x;
    const int i = hi & 511;
    const int t = threadIdx.x;
    const size_t base = (size_t)hi * C_;
    const size_t stride = (size_t)H_ * C_ * C_;
    float v0 = 0.f, v1 = 0.f;
    #pragma unroll
    for (int ksp = 0; ksp < 4; ++ksp) {
        v0 += __builtin_nontemporal_load(&partial[ksp * stride + base + t]);
        v1 += __builtin_nontemporal_load(&partial[ksp * stride + base + t + 256]);
    }
    const float mi = mask[i];
    const float keep = 1.0f - mi;
    v0 = v0 * keep + mi * (-10000.0f);
    v1 = v1 * keep + mi * (-10000.0f);

    float m = fmaxf(v0, v1);
    #pragma unroll
    for (int off = 32; off > 0; off >>= 1) m = fmaxf(m, __shfl_xor(m, off));
    __shared__ float red[4];
    if ((t & 63) == 0) red[t >> 6] = m;
    __syncthreads();
    m = fmaxf(fmaxf(red[0], red[1]), fmaxf(red[2], red[3]));

    const float e0 = expf(v0 - m), e1 = expf(v1 - m);
    float s = e0 + e1;
    #pragma unroll
    for (int off = 32; off > 0; off >>= 1) s += __shfl_xor(s, off);
    __syncthreads();
    if ((t & 63) == 0) red[t >> 6] = s;
    __syncthreads();
    s = red[0] + red[1] + red[2] + red[3];

    const float inv = 1.0f / s;
    const float p0 = e0 * inv, p1 = e1 * inv;
    __builtin_nontemporal_store(p0, &probs[base + t]);
    __builtin_nontemporal_store(p1, &probs[base + t + 256]);
    Pb[base + t] = f2bf(p0);          // Pb small (4MB) and reused -> cached
    Pb[base + t + 256] = f2bf(p1);
}

// ---------------------------------------------------------------------------
// Context.  128x128 tile, 256 threads, 4096 blocks (one head per XCD).
// ---------------------------------------------------------------------------
__global__ __launch_bounds__(256) void context_mfma(
    const ushort* __restrict__ Pb, const ushort* __restrict__ vb,
    ushort* __restrict__ ctxb)
{
    __shared__ __align__(16) ushort S[24576];
    BUFS3;
    const int id = ((blockIdx.x & 7) * 512) + (blockIdx.x >> 3);
    const int i0 = (id & 3) * 128;          // i fastest: 4 blocks share vb panel
    const int n0 = ((id >> 2) & 127) * 128;
    const int h = id >> 9;
    PREAMBLE(wid >> 1, wid & 1);

    const ushort* Ab = Pb + ((size_t)h * C_ + i0) * C_;
    const ushort* Bb = vb + ((size_t)h * R_ * D_ + n0) * C_;

#define CSTG(i, Abuf, Bbuf) {                                   \
    const ushort* Ai = Ab + (i) * 32;                           \
    const ushort* Bi = Bb + (i) * 32;                           \
    SCH(Ai, C_, Abuf, t); SCH(Ai, C_, Abuf, t + 256);           \
    SCH(Bi, C_, Bbuf, t); SCH(Bi, C_, Bbuf, t + 256); }
    DBUFT(CSTG, 16);
    __syncthreads();   // staging reads done before repack alias

    #pragma unroll
    for (int fm = 0; fm < 4; ++fm)
        #pragma unroll
        for (int fn = 0; fn < 4; ++fn)
            #pragma unroll
            for (int rg = 0; rg < 4; ++rg) {
                const int m = wm * 64 + fm * 16 + lhi * 4 + rg;
                const int n = wn * 64 + fn * 16 + l15;
                S[m * RP + n] = f2bf(acc[fm][fn][rg]);
            }
    __syncthreads();

    #pragma unroll
    for (int c = 0; c < 8; ++c) {
        const int idx = t + 256 * c;
        const int mrow = idx >> 4, nl = (idx & 15) * 8;
        uint4 w = *(const uint4*)(S + mrow * RP + nl);
        const int n = n0 + nl;
        const int rr = n >> 5, d = n & 31;
        const size_t rc = (size_t)rr * C_ + i0 + mrow;
        *(uint4*)(ctxb + rc * E_ + h * D_ + d) = w;
    }
}

// ---------------------------------------------------------------------------
// Output projection.  128x128 tile, 256 threads, 4096 blocks, fp32 out.
// out stores non-temporal (terminal output, never re-read on device).
// ---------------------------------------------------------------------------
__global__ __launch_bounds__(256) void out_proj_mfma(
    const ushort* __restrict__ ctxb, const ushort* __restrict__ WoT,
    const float* __restrict__ bo, float* __restrict__ out)
{
    __shared__ __align__(16) ushort S[24576];
    BUFS3;
    float* Sf = (float*)S;                  // 128 x 68 fp32 repack (aliases)
    const int id = ((blockIdx.x & 7) * 512) + (blockIdx.x >> 3);
    const int n0 = (id & 1) * 128;
    const int rc0 = (id >> 1) * 128;
    PREAMBLE(wid >> 1, wid & 1);

    const ushort* Ab = ctxb + (size_t)rc0 * E_;
    const ushort* Bb = WoT + (size_t)n0 * E_;

#define OSTG(i, Abuf, Bbuf) {                                   \
    const ushort* Ai = Ab + (i) * 32;                           \
    const ushort* Bi = Bb + (i) * 32;                           \
    SCH(Ai, E_, Abuf, t); SCH(Ai, E_, Abuf, t + 256);           \
    SCH(Bi, E_, Bbuf, t); SCH(Bi, E_, Bbuf, t + 256); }
    DBUFT(OSTG, 8);
    __syncthreads();   // staging reads done before repack alias

    float bvv[4];
    #pragma unroll
    for (int fn = 0; fn < 4; ++fn)
        bvv[fn] = bo[n0 + wn * 64 + fn * 16 + l15];

    #pragma unroll
    for (int p = 0; p < 2; ++p) {
        #pragma unroll
        for (int fm = 0; fm < 4; ++fm)
            #pragma unroll
            for (int fh = 0; fh < 2; ++fh) {
                const int fn = 2 * p + fh;
                #pragma unroll
                for (int rg = 0; rg < 4; ++rg) {
                    const int m = wm * 64 + fm * 16 + lhi * 4 + rg;
                    const int s = wn * 32 + fh * 16 + l15;
                    Sf[m * 68 + s] = acc[fm][fn][rg] + bvv[fn];
                }
            }
        __syncthreads();
        #pragma unroll
        for (int c = 0; c < 8; ++c) {
            const int idx = t + 256 * c;
            const int row = idx >> 4, s0 = (idx & 15) * 4;
            float4 w = *(const float4*)(Sf + row * 68 + s0);
            const int ncol = n0 + (s0 >> 5) * 64 + (2 * p + ((s0 >> 4) & 1)) * 16 + (s0 & 15);
            nts_f4(out + ((size_t)rc0 + row) * E_ + ncol, w);
        }
        __syncthreads();
    }
}

// ---------------------------------------------------------------------------
extern "C" void kernel_launch(void* const* d_in, const int* in_sizes, int n_in,
                              void* d_out, int out_size, void* d_ws, size_t ws_size,
                              hipStream_t stream)
{
    const float* x    = (const float*)d_in[0];
    const float* mask = (const float*)d_in[1];
    const float* Wq   = (const float*)d_in[2];
    const float* bq   = (const float*)d_in[3];
    const float* Wk   = (const float*)d_in[4];
    const float* bk   = (const float*)d_in[5];
    const float* Wv   = (const float*)d_in[6];
    const float* bv   = (const float*)d_in[7];
    const float* Wo   = (const float*)d_in[8];
    const float* bo   = (const float*)d_in[9];

    float* out   = (float*)d_out;                       // [R,C,E] fp32
    float* probs = out + (size_t)RC_ * E_;              // [H,C,C] fp32

    char* ws = (char*)d_ws;
    ushort* qb      = (ushort*)(ws);                    // 128 MB  [h][r][c][d]
    ushort* kb      = (ushort*)(ws + 134217728ull);     // 128 MB  [h][r][c][d]
    ushort* vb      = (ushort*)(ws + 268435456ull);     // 128 MB  [h][r][d][c]
    ushort* ctxb    = (ushort*)(ws + 402653184ull);     // 128 MB  [rc][e]
    float*  partial = (float*)(ws + 536870912ull);      // 32 MB   [4][h][i][j]
    ushort* Pb      = (ushort*)(ws + 603979776ull);     // 4 MB    [h][i][j]
    ushort* WTqkv   = (ushort*)(ws + 608174080ull);     // 384 KB
    ushort* WoT     = (ushort*)(ws + 608567296ull);     // 128 KB

    convert_w<<<1024, 256, 0, stream>>>(Wq, Wk, Wv, Wo, WTqkv, WoT);
    qkv_mfma<<<12288, 512, 0, stream>>>(x, WTqkv, bq, bk, bv, mask, qb, kb, vb);
    logits_mfma<<<512, 256, 0, stream>>>(qb, kb, partial);
    softmax_kernel<<<4096, 256, 0, stream>>>(partial, mask, probs, Pb);
    context_mfma<<<4096, 256, 0, stream>>>(Pb, vb, ctxb);
    out_proj_mfma<<<4096, 256, 0, stream>>>(ctxb, WoT, bo, out);
}